// Round 8
// baseline (1079.976 us; speedup 1.0000x reference)
//
#include <hip/hip_runtime.h>
#include <hip/hip_bf16.h>
#include <stdint.h>

// ---------------- types / helpers ----------------
typedef __attribute__((ext_vector_type(4))) float f32x4;
typedef __attribute__((ext_vector_type(8))) short s16x8;          // MFMA bf16 frag
typedef __attribute__((ext_vector_type(8))) unsigned short u16x8;

#define LL 1024
#define DMODEL 2048
#define DI 4096
#define NSTATE 16
#define RDT 128
#define NEXP 8
#define IFF 5632

#define BM 128
#define BN 128
#define BK 32
#define G2CHUNK 2816   // moe_gemm2 K-split chunk (2 parts, NT=88 each: even for pair-unroll)
#define G2PARTS 2
#define MAXTILES 23    // worst-case sum over experts of ceil(ce/128), sum ce = 2048

__device__ inline unsigned short f2bf(float f) {            // fp32 -> bf16 RNE (bit ops)
  unsigned int u = __builtin_bit_cast(unsigned int, f);
  u += 0x7fffu + ((u >> 16) & 1u);
  return (unsigned short)(u >> 16);
}
__device__ inline unsigned short cvbf(float f) {            // compiler path (v_cvt capable)
  return __builtin_bit_cast(unsigned short, __float2bfloat16(f));
}
__device__ inline float upbf(unsigned short h) {
  return __builtin_bit_cast(float, (unsigned int)h << 16);
}
__device__ inline float wred64(float v) {
#pragma unroll
  for (int m = 32; m; m >>= 1) v += __shfl_xor(v, m, 64);
  return v;
}
__device__ inline f32x4 mfma16(s16x8 a, s16x8 b, f32x4 c) {
  return __builtin_amdgcn_mfma_f32_16x16x32_bf16(a, b, c, 0, 0, 0);
}
// LDS tile index: row-major [rows][32] bf16, XOR-swizzled 8-elem chunks (4-way max conflict)
__device__ inline int swz(int row, int chunk) {
  return row * 32 + (chunk ^ ((row & 3) << 3));
}
__device__ inline void cv8(f32x4 a, f32x4 b, u16x8& h) {
#pragma unroll
  for (int j = 0; j < 4; j++) { h[j] = cvbf(a[j]); h[4 + j] = cvbf(b[j]); }
}
__device__ inline void cv_split8(f32x4 a, f32x4 b, u16x8& h, u16x8& l) {
#pragma unroll
  for (int j = 0; j < 4; j++) {
    unsigned short hh = cvbf(a[j]); h[j] = hh; l[j] = cvbf(a[j] - upbf(hh));
    unsigned short hb = cvbf(b[j]); h[4 + j] = hb; l[4 + j] = cvbf(b[j] - upbf(hb));
  }
}
// Barrier WITHOUT the compiler's vmcnt(0) drain (T4-minimum): waits LDS ops only,
// prefetched global loads stay in flight. lgkmcnt(0) covers ds_writes AND ds_reads
// -> 1-barrier WAR argument on the double buffer holds. sched_barrier(0) pins
// ordering (rule #18).
__device__ inline void pipe_sync() {
  __builtin_amdgcn_sched_barrier(0);
  asm volatile("s_waitcnt lgkmcnt(0)" ::: "memory");
  __builtin_amdgcn_sched_barrier(0);
  __builtin_amdgcn_s_barrier();
  __builtin_amdgcn_sched_barrier(0);
}

// ---------------- RMSNorm (optionally fused residual-add) ----------------
__global__ __launch_bounds__(256) void rmsnorm_k(
    const float* __restrict__ x, const float* __restrict__ w,
    const float* __restrict__ addin, float* __restrict__ resout,
    float* __restrict__ f32out, unsigned short* __restrict__ hiout,
    unsigned short* __restrict__ loout, unsigned short* __restrict__ bfout)
{
  int t = blockIdx.x, tid = threadIdx.x;
  size_t base = (size_t)t * DMODEL + tid * 8;
  f32x4 v0 = *(const f32x4*)(x + base);
  f32x4 v1 = *(const f32x4*)(x + base + 4);
  if (addin) {
    v0 += *(const f32x4*)(addin + base);
    v1 += *(const f32x4*)(addin + base + 4);
  }
  float ss = 0.f;
#pragma unroll
  for (int j = 0; j < 4; j++) ss += v0[j]*v0[j] + v1[j]*v1[j];
  ss = wred64(ss);
  __shared__ float sred[4];
  if ((tid & 63) == 0) sred[tid >> 6] = ss;
  __syncthreads();
  ss = sred[0] + sred[1] + sred[2] + sred[3];
  float sc = rsqrtf(ss * (1.f / DMODEL) + 1e-6f);
  if (resout) {
    *(f32x4*)(resout + base) = v0;
    *(f32x4*)(resout + base + 4) = v1;
  }
  f32x4 w0 = *(const f32x4*)(w + tid * 8);
  f32x4 w1 = *(const f32x4*)(w + tid * 8 + 4);
  f32x4 o0 = v0 * sc * w0, o1 = v1 * sc * w1;
  if (f32out) {
    *(f32x4*)(f32out + base) = o0;
    *(f32x4*)(f32out + base + 4) = o1;
  }
  if (hiout) {
    u16x8 h, l;
    cv_split8(o0, o1, h, l);
    *(u16x8*)(hiout + base) = h;
    *(u16x8*)(loout + base) = l;
  }
  if (bfout) {
    u16x8 ob;
#pragma unroll
    for (int j = 0; j < 4; j++) { ob[j] = f2bf(o0[j]); ob[4 + j] = f2bf(o1[j]); }
    *(u16x8*)(bfout + base) = ob;
  }
}

// ---------------- split-bf16 GEMM (depth-2 prefetch, dbuf LDS, 1 raw barrier/tile) ----
template<int EPI, int PS>
__global__ __launch_bounds__(256) void gemm_split_k(
    const float* __restrict__ A, const unsigned short* __restrict__ Ah,
    const unsigned short* __restrict__ Al, const float* __restrict__ W,
    float* __restrict__ C, int M, int N, int K, int kchunk,
    const float* __restrict__ bias)
{
  __shared__ unsigned short sA[2][2][128 * 32];   // [dbuf][hi/lo]
  __shared__ unsigned short sB[2][2][128 * 32];
  int tid = threadIdx.x;
  int n0 = blockIdx.x * BN, m0 = blockIdx.y * BM;
  int kbase = blockIdx.z * kchunk;
  C += (size_t)blockIdx.z * M * N;
  int lane = tid & 63, wave = tid >> 6;
  int wm = (wave >> 1) * 64, wn = (wave & 1) * 64;
  int lrow = lane & 15, lk = (lane >> 4) * 8;
  int ar = tid >> 1, ac = (tid & 1) * 16;
  int arow = m0 + ar; if (arow >= M) arow = M - 1;
  int wrow = n0 + ar; if (wrow >= N) wrow = N - 1;
  const float* aptr = A + (size_t)arow * K + kbase + ac;            // unused if PS
  const unsigned short* ahp = Ah + (PS ? ((size_t)arow * K + kbase + ac) : 0);
  const unsigned short* alp = Al + (PS ? ((size_t)arow * K + kbase + ac) : 0);
  const float* wptr = W + (size_t)wrow * K + kbase + ac;
  const int NT = kchunk / BK;          // all callers: NT even, >= 4
  f32x4 ra0[4], ra1[4], rw0[4], rw1[4];
  u16x8 rah0[2], ral0[2], rah1[2], ral1[2];
  if constexpr (PS) {
    rah0[0] = *(const u16x8*)(ahp);      rah0[1] = *(const u16x8*)(ahp + 8);
    ral0[0] = *(const u16x8*)(alp);      ral0[1] = *(const u16x8*)(alp + 8);
    rah1[0] = *(const u16x8*)(ahp + BK); rah1[1] = *(const u16x8*)(ahp + BK + 8);
    ral1[0] = *(const u16x8*)(alp + BK); ral1[1] = *(const u16x8*)(alp + BK + 8);
  } else {
#pragma unroll
    for (int q = 0; q < 4; q++) {
      ra0[q] = *(const f32x4*)(aptr + 4 * q);
      ra1[q] = *(const f32x4*)(aptr + BK + 4 * q);
    }
  }
#pragma unroll
  for (int q = 0; q < 4; q++) {
    rw0[q] = *(const f32x4*)(wptr + 4 * q);
    rw1[q] = *(const f32x4*)(wptr + BK + 4 * q);
  }
  f32x4 acc[4][4] = {};
  int c0 = ac, c1 = ac + 8;

#define GS_STEP(PB, TT)                                                      \
  {                                                                          \
    if constexpr (PS) {                                                      \
      *(u16x8*)&sA[PB][0][swz(ar, c0)] = rah##PB[0];                         \
      *(u16x8*)&sA[PB][0][swz(ar, c1)] = rah##PB[1];                         \
      *(u16x8*)&sA[PB][1][swz(ar, c0)] = ral##PB[0];                         \
      *(u16x8*)&sA[PB][1][swz(ar, c1)] = ral##PB[1];                         \
    } else {                                                                 \
      u16x8 h0, l0, h1, l1;                                                  \
      cv_split8(ra##PB[0], ra##PB[1], h0, l0);                               \
      cv_split8(ra##PB[2], ra##PB[3], h1, l1);                               \
      *(u16x8*)&sA[PB][0][swz(ar, c0)] = h0;                                 \
      *(u16x8*)&sA[PB][1][swz(ar, c0)] = l0;                                 \
      *(u16x8*)&sA[PB][0][swz(ar, c1)] = h1;                                 \
      *(u16x8*)&sA[PB][1][swz(ar, c1)] = l1;                                 \
    }                                                                        \
    {                                                                        \
      u16x8 h0, l0, h1, l1;                                                  \
      cv_split8(rw##PB[0], rw##PB[1], h0, l0);                               \
      cv_split8(rw##PB[2], rw##PB[3], h1, l1);                               \
      *(u16x8*)&sB[PB][0][swz(ar, c0)] = h0;                                 \
      *(u16x8*)&sB[PB][1][swz(ar, c0)] = l0;                                 \
      *(u16x8*)&sB[PB][0][swz(ar, c1)] = h1;                                 \
      *(u16x8*)&sB[PB][1][swz(ar, c1)] = l1;                                 \
    }                                                                        \
    if ((TT) + 2 < NT) {                                                     \
      int kk = ((TT) + 2) * BK;                                              \
      if constexpr (PS) {                                                    \
        rah##PB[0] = *(const u16x8*)(ahp + kk);                              \
        rah##PB[1] = *(const u16x8*)(ahp + kk + 8);                          \
        ral##PB[0] = *(const u16x8*)(alp + kk);                              \
        ral##PB[1] = *(const u16x8*)(alp + kk + 8);                          \
      } else {                                                               \
        _Pragma("unroll")                                                    \
        for (int q = 0; q < 4; q++) ra##PB[q] = *(const f32x4*)(aptr + kk + 4 * q); \
      }                                                                      \
      _Pragma("unroll")                                                      \
      for (int q = 0; q < 4; q++) rw##PB[q] = *(const f32x4*)(wptr + kk + 4 * q); \
    }                                                                        \
    pipe_sync();                                                             \
    {                                                                        \
      s16x8 ah[4], al[4];                                                    \
      _Pragma("unroll")                                                      \
      for (int i = 0; i < 4; i++) {                                          \
        int r = wm + i * 16 + lrow;                                          \
        ah[i] = *(const s16x8*)&sA[PB][0][swz(r, lk)];                       \
        al[i] = *(const s16x8*)&sA[PB][1][swz(r, lk)];                       \
      }                                                                      \
      _Pragma("unroll")                                                      \
      for (int ni = 0; ni < 4; ni++) {                                       \
        int r = wn + ni * 16 + lrow;                                         \
        s16x8 bh = *(const s16x8*)&sB[PB][0][swz(r, lk)];                    \
        s16x8 bl = *(const s16x8*)&sB[PB][1][swz(r, lk)];                    \
        _Pragma("unroll")                                                    \
        for (int mi = 0; mi < 4; mi++) {                                     \
          f32x4 tc = acc[mi][ni];                                            \
          tc = mfma16(al[mi], bh, tc);                                       \
          tc = mfma16(ah[mi], bl, tc);                                       \
          tc = mfma16(ah[mi], bh, tc);                                       \
          acc[mi][ni] = tc;                                                  \
        }                                                                    \
      }                                                                      \
    }                                                                        \
  }

  for (int t = 0; t < NT; t += 2) { GS_STEP(0, t) GS_STEP(1, t + 1) }
#undef GS_STEP

  int rb = wm + (lane >> 4) * 4, cb = wn + (lane & 15);
#pragma unroll
  for (int mi = 0; mi < 4; mi++)
#pragma unroll
    for (int ni = 0; ni < 4; ni++) {
      int col = n0 + cb + ni * 16;
      if (col >= N) continue;
#pragma unroll
      for (int j = 0; j < 4; j++) {
        int row = m0 + rb + mi * 16 + j;
        if (row >= M) continue;
        float v = acc[mi][ni][j];
        if (EPI == 1) { v += bias[col]; v = (v > 20.f) ? v : log1pf(expf(v)); }
        C[(size_t)row * N + col] = v;
      }
    }
}

// ---------------- split-K partial reduction ----------------
__global__ void reduce_parts_k(const float* __restrict__ src, float* __restrict__ dst,
                               int len, int parts)
{
  int i = (blockIdx.x * 256 + threadIdx.x) * 4;
  if (i >= len) return;
  f32x4 s = *(const f32x4*)(src + i);
  for (int p = 1; p < parts; p++) s += *(const f32x4*)(src + (size_t)p * len + i);
  *(f32x4*)(dst + i) = s;
}

// ---------------- causal depthwise conv (K=4) + SiLU ----------------
__global__ __launch_bounds__(256) void conv_silu_k(
    const float* __restrict__ xz, const float* __restrict__ cw,
    const float* __restrict__ cb, float* __restrict__ xc)
{
  int idx = blockIdx.x * 256 + threadIdx.x;      // t*4096 + d
  int t = idx >> 12, d = idx & (DI - 1);
  f32x4 w = *(const f32x4*)(cw + d * 4);
  float acc = cb[d];
#pragma unroll
  for (int k = 0; k < 4; k++) {
    int ts = t - 3 + k;
    if (ts >= 0) acc = fmaf(xz[(size_t)ts * 8192 + d], w[k], acc);
  }
  float v = acc / (1.f + __expf(-acc));
  xc[idx] = v;
}

// ---------------- dt/B/C rmsnorms (row of 160 = 128+16+16) ----------------
__global__ void dtbc_norm_k(const float* __restrict__ xdb,
    const float* __restrict__ dtw, const float* __restrict__ bw, const float* __restrict__ cw,
    float* __restrict__ dtr, float* __restrict__ Bm, float* __restrict__ Cm)
{
  int t = blockIdx.x, lane = threadIdx.x;   // 64 threads
  const float* row = xdb + (size_t)t * 160;
  float v1 = row[lane], v2 = row[64 + lane];
  float vb = (lane < 32) ? row[128 + lane] : 0.f;
  float sd = wred64(v1 * v1 + v2 * v2);
  float sb = wred64((lane < 16) ? vb * vb : 0.f);
  float sc = wred64((lane >= 16 && lane < 32) ? vb * vb : 0.f);
  float scd = rsqrtf(sd * (1.f / 128) + 1e-6f);
  dtr[(size_t)t * 128 + lane]      = v1 * scd * dtw[lane];
  dtr[(size_t)t * 128 + 64 + lane] = v2 * scd * dtw[64 + lane];
  if (lane < 16)      Bm[t * 16 + lane]      = vb * rsqrtf(sb * (1.f / 16) + 1e-6f) * bw[lane];
  else if (lane < 32) Cm[t * 16 + lane - 16] = vb * rsqrtf(sc * (1.f / 16) + 1e-6f) * cw[lane - 16];
}

// ---------------- selective scan; y written IN PLACE over xc ----------------
__global__ __launch_bounds__(256) void scan_k(
    const float* __restrict__ dt, float* __restrict__ xcy,
    const float* __restrict__ xz, const float* __restrict__ Bm,
    const float* __restrict__ Cm, const float* __restrict__ A_log,
    const float* __restrict__ Dp)
{
  __shared__ float sdt[64][16], sxc[64][16], sz[64][16], sB[64][16], sC[64][16], sy[64][16];
  int tid = threadIdx.x;
  int dl = tid >> 4, n = tid & 15;
  int d0 = blockIdx.x * 16;
  int d = d0 + dl;
  float a = -__expf(A_log[d * 16 + n]);
  float dpar = Dp[d];
  float h = 0.f;
  for (int t0 = 0; t0 < LL; t0 += 64) {
#pragma unroll
    for (int i = 0; i < 4; i++) {
      int idx = i * 256 + tid;
      int tt = idx >> 4, c = idx & 15;
      int gt = t0 + tt;
      sdt[tt][c] = dt[(size_t)gt * DI + d0 + c];
      sxc[tt][c] = xcy[(size_t)gt * DI + d0 + c];
      sz[tt][c]  = xz[(size_t)gt * 8192 + DI + d0 + c];
      sB[tt][c]  = Bm[gt * 16 + c];
      sC[tt][c]  = Cm[gt * 16 + c];
    }
    __syncthreads();
    for (int tt = 0; tt < 64; tt++) {
      float dtv = sdt[tt][dl];
      float dA = __expf(dtv * a);
      h = h * dA + dtv * sxc[tt][dl] * sB[tt][n];
      float yc = h * sC[tt][n];
      yc += __shfl_xor(yc, 1, 64);
      yc += __shfl_xor(yc, 2, 64);
      yc += __shfl_xor(yc, 4, 64);
      yc += __shfl_xor(yc, 8, 64);
      if (n == 0) {
        float xv = sxc[tt][dl], zv = sz[tt][dl];
        sy[tt][dl] = (yc + xv * dpar) * (zv / (1.f + __expf(-zv)));
      }
    }
    __syncthreads();
#pragma unroll
    for (int i = 0; i < 4; i++) {
      int idx = i * 256 + tid;
      int tt = idx >> 4, c = idx & 15;
      xcy[(size_t)(t0 + tt) * DI + d0 + c] = sy[tt][c];
    }
    __syncthreads();
  }
}

// ---------------- router: logits + softmax + top-2 ----------------
__global__ void router_topk_k(const float* __restrict__ hs2,
                              const float* __restrict__ rw,
                              int* __restrict__ topi, float* __restrict__ topv)
{
  int t = blockIdx.x, lane = threadIdx.x;   // 64 threads
  float acc[NEXP] = {};
  const float* xr = hs2 + (size_t)t * DMODEL;
  for (int i = lane; i < DMODEL; i += 64) {
    float x = xr[i];
#pragma unroll
    for (int e = 0; e < NEXP; e++) acc[e] += x * rw[e * DMODEL + i];
  }
#pragma unroll
  for (int e = 0; e < NEXP; e++) acc[e] = wred64(acc[e]);
  if (lane == 0) {
    float mx = acc[0];
#pragma unroll
    for (int e = 1; e < NEXP; e++) mx = fmaxf(mx, acc[e]);
    float p[NEXP], s = 0.f;
#pragma unroll
    for (int e = 0; e < NEXP; e++) { p[e] = expf(acc[e] - mx); s += p[e]; }
    float inv = 1.f / s;
#pragma unroll
    for (int e = 0; e < NEXP; e++) p[e] *= inv;
    int i0 = 0;
#pragma unroll
    for (int e = 1; e < NEXP; e++) if (p[e] > p[i0]) i0 = e;
    int i1 = (i0 == 0) ? 1 : 0;
#pragma unroll
    for (int e = 0; e < NEXP; e++) if (e != i0 && p[e] > p[i1]) i1 = e;
    topi[2 * t] = i0; topi[2 * t + 1] = i1;
    topv[2 * t] = p[i0]; topv[2 * t + 1] = p[i1];
  }
}

// ---------------- deterministic per-expert token lists + compact tile list ----------
__global__ void build_lists_k(const int* __restrict__ topi, const float* __restrict__ topv,
                              int* __restrict__ tok, float* __restrict__ gate,
                              int* __restrict__ slot, int* __restrict__ cnt,
                              int* __restrict__ offs, int* __restrict__ mt)
{
  int lane = threadIdx.x;   // 64
  int base[NEXP] = {};
  for (int t0 = 0; t0 < LL; t0 += 64) {
    int t = t0 + lane;
    int i0 = topi[2 * t], i1 = topi[2 * t + 1];
    float p0 = topv[2 * t], p1 = topv[2 * t + 1];
    unsigned long long below = (1ull << lane) - 1ull;
#pragma unroll
    for (int e = 0; e < NEXP; e++) {
      unsigned long long m0 = __ballot(i0 == e);
      if (i0 == e) {
        int pos = base[e] + __popcll(m0 & below);
        tok[e * LL + pos] = t; gate[e * LL + pos] = p0; slot[e * LL + pos] = 0;
      }
      base[e] += __popcll(m0);
      unsigned long long m1 = __ballot(i1 == e);
      if (i1 == e) {
        int pos = base[e] + __popcll(m1 & below);
        tok[e * LL + pos] = t; gate[e * LL + pos] = p1; slot[e * LL + pos] = 1;
      }
      base[e] += __popcll(m1);
    }
  }
  if (lane < NEXP) cnt[lane] = base[lane];
  if (lane == 0) {
    int o = 0;
#pragma unroll
    for (int e = 0; e < NEXP; e++) { offs[e] = o; o += base[e]; }
    // compact (expert, m0) tile list: mt[0] = count, then pairs (e, m0)
    int f = 0;
#pragma unroll
    for (int e = 0; e < NEXP; e++)
      for (int m0 = 0; m0 < base[e]; m0 += BM) {
        mt[1 + 2 * f] = e; mt[2 + 2 * f] = m0; f++;
      }
    mt[0] = f;
  }
}

// ---------------- MoE phase 1 (compact grid, BM=128 x BN=64, depth-2) ----------------
__global__ __launch_bounds__(256, 3) void moe_gemm1_k(
    const unsigned short* __restrict__ hs2b,
    const float* __restrict__ w1, const float* __restrict__ w3,
    unsigned short* __restrict__ act,
    const int* __restrict__ tok, const int* __restrict__ cnt,
    const int* __restrict__ offs, const int* __restrict__ mt)
{
  int zt = blockIdx.z;
  if (zt >= mt[0]) return;
  int e  = mt[1 + 2 * zt];
  int m0 = mt[2 + 2 * zt];
  int ce = cnt[e];
  int n0 = blockIdx.x * 64;
  __shared__ unsigned short sA[2][128 * 32];
  __shared__ unsigned short sB1[2][64 * 32];
  __shared__ unsigned short sB2[2][64 * 32];
  const float* W1 = w1 + (size_t)e * IFF * DMODEL;
  const float* W3 = w3 + (size_t)e * IFF * DMODEL;
  int tid = threadIdx.x;
  int lane = tid & 63, wave = tid >> 6;
  int wm = (wave >> 1) * 64, wn = (wave & 1) * 32;
  int lrow = lane & 15, lk = (lane >> 4) * 8;
  int ar = tid >> 1, ac = (tid & 1) * 16;
  int br = tid >> 2, bc = (tid & 3) * 8;
  bool av = (m0 + ar) < ce;
  const unsigned short* aptr = hs2b + (size_t)(av ? tok[e * LL + m0 + ar] : 0) * DMODEL + ac;
  const float* w1p = W1 + (size_t)(n0 + br) * DMODEL + bc;
  const float* w3p = W3 + (size_t)(n0 + br) * DMODEL + bc;
  u16x8 ua0[2], ua1[2];
  f32x4 w1r0[2], w1r1[2], w3r0[2], w3r1[2];
  ua0[0] = *(const u16x8*)(aptr);      ua0[1] = *(const u16x8*)(aptr + 8);
  ua1[0] = *(const u16x8*)(aptr + BK); ua1[1] = *(const u16x8*)(aptr + BK + 8);
  w1r0[0] = *(const f32x4*)(w1p);      w1r0[1] = *(const f32x4*)(w1p + 4);
  w1r1[0] = *(const f32x4*)(w1p + BK); w1r1[1] = *(const f32x4*)(w1p + BK + 4);
  w3r0[0] = *(const f32x4*)(w3p);      w3r0[1] = *(const f32x4*)(w3p + 4);
  w3r1[0] = *(const f32x4*)(w3p + BK); w3r1[1] = *(const f32x4*)(w3p + BK + 4);
  f32x4 acc1[4][2] = {}, acc2[4][2] = {};
  int c0 = ac, c1 = ac + 8;
  const int NT = DMODEL / BK;   // 64, even

#define G1_STEP(PB, TT)                                                      \
  {                                                                          \
    *(u16x8*)&sA[PB][swz(ar, c0)] = ua##PB[0];                               \
    *(u16x8*)&sA[PB][swz(ar, c1)] = ua##PB[1];                               \
    u16x8 h;                                                                 \
    cv8(w1r##PB[0], w1r##PB[1], h); *(u16x8*)&sB1[PB][swz(br, bc)] = h;      \
    cv8(w3r##PB[0], w3r##PB[1], h); *(u16x8*)&sB2[PB][swz(br, bc)] = h;      \
    if ((TT) + 2 < NT) {                                                     \
      int kk = ((TT) + 2) * BK;                                              \
      ua##PB[0] = *(const u16x8*)(aptr + kk);                                \
      ua##PB[1] = *(const u16x8*)(aptr + kk + 8);                            \
      w1r##PB[0] = *(const f32x4*)(w1p + kk);                                \
      w1r##PB[1] = *(const f32x4*)(w1p + kk + 4);                            \
      w3r##PB[0] = *(const f32x4*)(w3p + kk);                                \
      w3r##PB[1] = *(const f32x4*)(w3p + kk + 4);                            \
    }                                                                        \
    pipe_sync();                                                             \
    {                                                                        \
      s16x8 af[4];                                                           \
      _Pragma("unroll")                                                      \
      for (int i = 0; i < 4; i++)                                            \
        af[i] = *(const s16x8*)&sA[PB][swz(wm + i * 16 + lrow, lk)];         \
      _Pragma("unroll")                                                      \
      for (int ni = 0; ni < 2; ni++) {                                       \
        int r = wn + ni * 16 + lrow;                                         \
        s16x8 b1 = *(const s16x8*)&sB1[PB][swz(r, lk)];                      \
        s16x8 b2 = *(const s16x8*)&sB2[PB][swz(r, lk)];                      \
        _Pragma("unroll")                                                    \
        for (int mi = 0; mi < 4; mi++) acc1[mi][ni] = mfma16(af[mi], b1, acc1[mi][ni]); \
        _Pragma("unroll")                                                    \
        for (int mi = 0; mi < 4; mi++) acc2[mi][ni] = mfma16(af[mi], b2, acc2[mi][ni]); \
      }                                                                      \
    }                                                                        \
  }

  for (int t = 0; t < NT; t += 2) { G1_STEP(0, t) G1_STEP(1, t + 1) }
#undef G1_STEP

  int rb = wm + (lane >> 4) * 4, cb = wn + (lane & 15);
  int obase = offs[e];
#pragma unroll
  for (int mi = 0; mi < 4; mi++)
#pragma unroll
    for (int j = 0; j < 4; j++) {
      int row = m0 + rb + mi * 16 + j;
      if (row >= ce) continue;
#pragma unroll
      for (int ni = 0; ni < 2; ni++) {
        int col = n0 + cb + ni * 16;
        float g = acc1[mi][ni][j], u = acc2[mi][ni][j];
        float aval = (g / (1.f + __expf(-g))) * u;
        act[(size_t)(obase + row) * IFF + col] = f2bf(aval);
      }
    }
}

// ---------------- MoE phase 2 (compact grid, BM=128 x BN=64, depth-2, K-split) --------
__global__ __launch_bounds__(256, 4) void moe_gemm2_k(
    const unsigned short* __restrict__ act, const float* __restrict__ w2,
    float* __restrict__ g2p,
    const int* __restrict__ tok, const float* __restrict__ gate,
    const int* __restrict__ slot, const int* __restrict__ cnt,
    const int* __restrict__ offs, const int* __restrict__ mt)
{
  int zt = blockIdx.z;
  if (zt >= mt[0]) return;
  int e  = mt[1 + 2 * zt];
  int m0 = mt[2 + 2 * zt];
  int ce = cnt[e];
  int part = blockIdx.y;
  int n0 = blockIdx.x * 64;
  int kbase = part * G2CHUNK;
  const int NT = G2CHUNK >> 5;   // 88, even
  __shared__ unsigned short sA[2][128 * 32];
  __shared__ unsigned short sB[2][64 * 32];
  const float* W = w2 + (size_t)e * DMODEL * IFF;
  int obase = offs[e];
  int tid = threadIdx.x;
  int lane = tid & 63, wave = tid >> 6;
  int wm = (wave >> 1) * 64, wn = (wave & 1) * 32;
  int lrow = lane & 15, lk = (lane >> 4) * 8;
  int ar = tid >> 1, ac = (tid & 1) * 16;
  int br = tid >> 2, bc = (tid & 3) * 8;
  bool av = (m0 + ar) < ce;
  const unsigned short* aptr = act + (size_t)(obase + (av ? (m0 + ar) : 0)) * IFF + kbase + ac;
  const float* wp = W + (size_t)(n0 + br) * IFF + kbase + bc;
  u16x8 ua0[2], ua1[2];
  f32x4 rw0[2], rw1[2];
  ua0[0] = *(const u16x8*)(aptr);      ua0[1] = *(const u16x8*)(aptr + 8);
  ua1[0] = *(const u16x8*)(aptr + BK); ua1[1] = *(const u16x8*)(aptr + BK + 8);
  rw0[0] = *(const f32x4*)(wp);        rw0[1] = *(const f32x4*)(wp + 4);
  rw1[0] = *(const f32x4*)(wp + BK);   rw1[1] = *(const f32x4*)(wp + BK + 4);
  f32x4 acc[4][2] = {};
  int c0 = ac, c1 = ac + 8;

#define G2_STEP(PB, TT)                                                      \
  {                                                                          \
    *(u16x8*)&sA[PB][swz(ar, c0)] = ua##PB[0];                               \
    *(u16x8*)&sA[PB][swz(ar, c1)] = ua##PB[1];                               \
    u16x8 h;                                                                 \
    cv8(rw##PB[0], rw##PB[1], h); *(u16x8*)&sB[PB][swz(br, bc)] = h;         \
    if ((TT) + 2 < NT) {                                                     \
      int kk = ((TT) + 2) * BK;                                              \
      ua##PB[0] = *(const u16x8*)(aptr + kk);                                \
      ua##PB[1] = *(const u16x8*)(aptr + kk + 8);                            \
      rw##PB[0] = *(const f32x4*)(wp + kk);                                  \
      rw##PB[1] = *(const f32x4*)(wp + kk + 4);                              \
    }                                                                        \
    pipe_sync();                                                             \
    {                                                                        \
      s16x8 af[4];                                                           \
      _Pragma("unroll")                                                      \
      for (int i = 0; i < 4; i++)                                            \
        af[i] = *(const s16x8*)&sA[PB][swz(wm + i * 16 + lrow, lk)];         \
      _Pragma("unroll")                                                      \
      for (int ni = 0; ni < 2; ni++) {                                       \
        s16x8 b = *(const s16x8*)&sB[PB][swz(wn + ni * 16 + lrow, lk)];      \
        _Pragma("unroll")                                                    \
        for (int mi = 0; mi < 4; mi++) acc[mi][ni] = mfma16(af[mi], b, acc[mi][ni]); \
      }                                                                      \
    }                                                                        \
  }

  for (int t = 0; t < NT; t += 2) { G2_STEP(0, t) G2_STEP(1, t + 1) }
#undef G2_STEP

  int rb = wm + (lane >> 4) * 4, cb = wn + (lane & 15);
#pragma unroll
  for (int mi = 0; mi < 4; mi++)
#pragma unroll
    for (int j = 0; j < 4; j++) {
      int row = m0 + rb + mi * 16 + j;
      if (row >= ce) continue;
      int t = tok[e * LL + row];
      float g = gate[e * LL + row];
      int s = slot[e * LL + row];
      float* dst = g2p + ((size_t)(part * 2 + s) * LL + t) * DMODEL + n0 + cb;
#pragma unroll
      for (int ni = 0; ni < 2; ni++) dst[ni * 16] = acc[mi][ni][j] * g;
    }
}

// ---------------- combine the (part,slot) planes ----------------
__global__ void moe_combine_k(const float* __restrict__ ys, float* __restrict__ out) {
  size_t i = ((size_t)blockIdx.x * 256 + threadIdx.x) * 4;
  f32x4 s = *(const f32x4*)(ys + i);
#pragma unroll
  for (int p = 1; p < 2 * G2PARTS; p++)
    s += *(const f32x4*)(ys + (size_t)p * LL * DMODEL + i);
  *(f32x4*)(out + i) = s;
}

// ---------------- launch ----------------
extern "C" void kernel_launch(void* const* d_in, const int* in_sizes, int n_in,
                              void* d_out, int out_size, void* d_ws, size_t ws_size,
                              hipStream_t stream)
{
  (void)in_sizes; (void)n_in; (void)out_size; (void)ws_size;
  const float* hidden     = (const float*)d_in[0];
  const float* ln_in_w    = (const float*)d_in[1];
  const float* in_proj_w  = (const float*)d_in[2];
  const float* conv_w     = (const float*)d_in[3];
  const float* conv_b     = (const float*)d_in[4];
  const float* x_proj_w   = (const float*)d_in[5];
  const float* dt_ln_w    = (const float*)d_in[6];
  const float* b_ln_w     = (const float*)d_in[7];
  const float* c_ln_w     = (const float*)d_in[8];
  const float* dt_proj_w  = (const float*)d_in[9];
  const float* dt_proj_b  = (const float*)d_in[10];
  const float* A_log      = (const float*)d_in[11];
  const float* D_param    = (const float*)d_in[12];
  const float* out_proj_w = (const float*)d_in[13];
  const float* ln_ff_w    = (const float*)d_in[14];
  const float* router_w   = (const float*)d_in[15];
  const float* w1         = (const float*)d_in[16];
  const float* w3         = (const float*)d_in[17];
  const float* w2         = (const float*)d_in[18];
  float* moe_out  = (float*)d_out;
  float* residual = (float*)d_out + (size_t)LL * DMODEL;

  char* p = (char*)d_ws;
  auto alloc = [&](size_t bytes) { char* r = p; p += (bytes + 255) & ~(size_t)255; return r; };
  unsigned short* hs_hi  = (unsigned short*)alloc((size_t)LL * DMODEL * 2);
  unsigned short* hs_lo  = (unsigned short*)alloc((size_t)LL * DMODEL * 2);
  float* xz              = (float*)alloc((size_t)LL * 2 * DI * 4);   // aliased: out_parts, act_buf
  float* xc              = (float*)alloc((size_t)LL * DI * 4);       // conv out; scan writes y in place
  float* xdb             = (float*)alloc((size_t)LL * 160 * 4);
  float* dtr             = (float*)alloc((size_t)LL * 128 * 4);
  float* Bm              = (float*)alloc((size_t)LL * 16 * 4);
  float* Cm              = (float*)alloc((size_t)LL * 16 * 4);
  float* dt_full         = (float*)alloc((size_t)LL * DI * 4);       // aliased: xdb_parts
  float* mamba_out       = (float*)alloc((size_t)LL * DMODEL * 4);
  float* hs2_f           = (float*)alloc((size_t)LL * DMODEL * 4);
  unsigned short* hs2_bf = (unsigned short*)alloc((size_t)LL * DMODEL * 2);
  int* topi              = (int*)alloc(LL * 2 * 4);
  float* topv            = (float*)alloc(LL * 2 * 4);
  int* tok               = (int*)alloc(NEXP * LL * 4);
  float* gate            = (float*)alloc(NEXP * LL * 4);
  int* slot              = (int*)alloc(NEXP * LL * 4);
  int* cnt               = (int*)alloc(256);
  int* offs              = (int*)alloc(256);
  int* mt                = (int*)alloc((1 + 2 * 64) * 4);   // tile list: count + (e,m0) pairs
  // aliases (lifetimes strictly ordered by stream order):
  float* xdb_parts        = dt_full;               // 16 x 0.655 MB = 10.5 <= 16.78
  float* out_parts        = xz;                    // 4 x 8.39 MB = 33.55 (xz dead after scan)
  unsigned short* act_buf = (unsigned short*)xz;   // 23.07 MB (after out-reduce)
  float* g2parts          = (float*)((char*)act_buf + (size_t)2 * LL * IFF * 2); // 33.55 MB
  //   g2parts spans [23.1, 56.6) MB rel xz: overlaps xz-tail/xc/xdb/dtr — all dead
  //   by moe_gemm2 time; hs2_bf / tok / gate / slot / cnt / offs / mt live beyond it.

  rmsnorm_k<<<LL, 256, 0, stream>>>(hidden, ln_in_w, nullptr, nullptr, nullptr, hs_hi, hs_lo, nullptr);
  gemm_split_k<0, 1><<<dim3(64, 8, 1), 256, 0, stream>>>(nullptr, hs_hi, hs_lo, in_proj_w, xz, LL, 2 * DI, DMODEL, DMODEL, nullptr);
  conv_silu_k<<<(LL * DI) / 256, 256, 0, stream>>>(xz, conv_w, conv_b, xc);
  gemm_split_k<0, 0><<<dim3(2, 8, 16), 256, 0, stream>>>(xc, nullptr, nullptr, x_proj_w, xdb_parts, LL, 160, DI, DI / 16, nullptr);
  reduce_parts_k<<<(LL * 160) / 1024, 256, 0, stream>>>(xdb_parts, xdb, LL * 160, 16);
  dtbc_norm_k<<<LL, 64, 0, stream>>>(xdb, dt_ln_w, b_ln_w, c_ln_w, dtr, Bm, Cm);
  gemm_split_k<1, 0><<<dim3(32, 8, 1), 256, 0, stream>>>(dtr, nullptr, nullptr, dt_proj_w, dt_full, LL, DI, RDT, RDT, dt_proj_b);
  scan_k<<<DI / 16, 256, 0, stream>>>(dt_full, xc, xz, Bm, Cm, A_log, D_param);
  gemm_split_k<0, 0><<<dim3(16, 8, 4), 256, 0, stream>>>(xc, nullptr, nullptr, out_proj_w, out_parts, LL, DMODEL, DI, DI / 4, nullptr);
  reduce_parts_k<<<(LL * DMODEL) / 1024, 256, 0, stream>>>(out_parts, mamba_out, LL * DMODEL, 4);
  rmsnorm_k<<<LL, 256, 0, stream>>>(mamba_out, ln_ff_w, hidden, residual, hs2_f, nullptr, nullptr, hs2_bf);
  router_topk_k<<<LL, 64, 0, stream>>>(hs2_f, router_w, topi, topv);
  build_lists_k<<<1, 64, 0, stream>>>(topi, topv, tok, gate, slot, cnt, offs, mt);
  moe_gemm1_k<<<dim3(88, 1, MAXTILES), 256, 0, stream>>>(hs2_bf, w1, w3, act_buf, tok, cnt, offs, mt);
  moe_gemm2_k<<<dim3(32, G2PARTS, MAXTILES), 256, 0, stream>>>(act_buf, w2, g2parts, tok, gate, slot, cnt, offs, mt);
  moe_combine_k<<<(LL * DMODEL) / (256 * 4), 256, 0, stream>>>(g2parts, moe_out);
}

// Round 9
// 1008.982 us; speedup vs baseline: 1.0704x; 1.0704x over previous
//
#include <hip/hip_runtime.h>
#include <hip/hip_bf16.h>
#include <stdint.h>

// ---------------- types / helpers ----------------
typedef __attribute__((ext_vector_type(4))) float f32x4;
typedef __attribute__((ext_vector_type(8))) short s16x8;          // MFMA bf16 frag
typedef __attribute__((ext_vector_type(8))) unsigned short u16x8;

#define LL 1024
#define DMODEL 2048
#define DI 4096
#define NSTATE 16
#define RDT 128
#define NEXP 8
#define IFF 5632

#define BM 128
#define BN 128
#define BK 32
#define G2CHUNK 2816   // moe_gemm2 K-split chunk (2 parts; BK=64 -> NT=44 even)
#define G2PARTS 2
#define MAXTILES 23    // worst-case sum over experts of ceil(ce/128), sum ce = 2048

__device__ inline unsigned short f2bf(float f) {            // fp32 -> bf16 RNE (bit ops)
  unsigned int u = __builtin_bit_cast(unsigned int, f);
  u += 0x7fffu + ((u >> 16) & 1u);
  return (unsigned short)(u >> 16);
}
__device__ inline unsigned short cvbf(float f) {            // compiler path (v_cvt capable)
  return __builtin_bit_cast(unsigned short, __float2bfloat16(f));
}
__device__ inline float upbf(unsigned short h) {
  return __builtin_bit_cast(float, (unsigned int)h << 16);
}
__device__ inline float wred64(float v) {
#pragma unroll
  for (int m = 32; m; m >>= 1) v += __shfl_xor(v, m, 64);
  return v;
}
__device__ inline f32x4 mfma16(s16x8 a, s16x8 b, f32x4 c) {
  return __builtin_amdgcn_mfma_f32_16x16x32_bf16(a, b, c, 0, 0, 0);
}
// LDS tile index, 32-elem rows (mamba GEMMs): XOR-swizzle 8-elem granules
__device__ inline int swz(int row, int chunk) {
  return row * 32 + (chunk ^ ((row & 3) << 3));
}
// LDS tile index, 64-elem rows (MoE GEMMs, BK=64): granule bits 3..5 XOR row&7
// -> 16-lane column reads spread over 8 granules x 4 banks = 2 lanes/bank (free, m136)
__device__ inline int swz64(int row, int chunk) {
  return row * 64 + (chunk ^ ((row & 7) << 3));
}
__device__ inline void cv8(f32x4 a, f32x4 b, u16x8& h) {
#pragma unroll
  for (int j = 0; j < 4; j++) { h[j] = cvbf(a[j]); h[4 + j] = cvbf(b[j]); }
}
__device__ inline void cv_split8(f32x4 a, f32x4 b, u16x8& h, u16x8& l) {
#pragma unroll
  for (int j = 0; j < 4; j++) {
    unsigned short hh = cvbf(a[j]); h[j] = hh; l[j] = cvbf(a[j] - upbf(hh));
    unsigned short hb = cvbf(b[j]); h[4 + j] = hb; l[4 + j] = cvbf(b[j] - upbf(hb));
  }
}
// Barrier WITHOUT the compiler's vmcnt(0) drain (T4-minimum).
__device__ inline void pipe_sync() {
  __builtin_amdgcn_sched_barrier(0);
  asm volatile("s_waitcnt lgkmcnt(0)" ::: "memory");
  __builtin_amdgcn_sched_barrier(0);
  __builtin_amdgcn_s_barrier();
  __builtin_amdgcn_sched_barrier(0);
}

// ---------------- RMSNorm (optionally fused residual-add) ----------------
__global__ __launch_bounds__(256) void rmsnorm_k(
    const float* __restrict__ x, const float* __restrict__ w,
    const float* __restrict__ addin, float* __restrict__ resout,
    float* __restrict__ f32out, unsigned short* __restrict__ hiout,
    unsigned short* __restrict__ loout, unsigned short* __restrict__ bfout)
{
  int t = blockIdx.x, tid = threadIdx.x;
  size_t base = (size_t)t * DMODEL + tid * 8;
  f32x4 v0 = *(const f32x4*)(x + base);
  f32x4 v1 = *(const f32x4*)(x + base + 4);
  if (addin) {
    v0 += *(const f32x4*)(addin + base);
    v1 += *(const f32x4*)(addin + base + 4);
  }
  float ss = 0.f;
#pragma unroll
  for (int j = 0; j < 4; j++) ss += v0[j]*v0[j] + v1[j]*v1[j];
  ss = wred64(ss);
  __shared__ float sred[4];
  if ((tid & 63) == 0) sred[tid >> 6] = ss;
  __syncthreads();
  ss = sred[0] + sred[1] + sred[2] + sred[3];
  float sc = rsqrtf(ss * (1.f / DMODEL) + 1e-6f);
  if (resout) {
    *(f32x4*)(resout + base) = v0;
    *(f32x4*)(resout + base + 4) = v1;
  }
  f32x4 w0 = *(const f32x4*)(w + tid * 8);
  f32x4 w1 = *(const f32x4*)(w + tid * 8 + 4);
  f32x4 o0 = v0 * sc * w0, o1 = v1 * sc * w1;
  if (f32out) {
    *(f32x4*)(f32out + base) = o0;
    *(f32x4*)(f32out + base + 4) = o1;
  }
  if (hiout) {
    u16x8 h, l;
    cv_split8(o0, o1, h, l);
    *(u16x8*)(hiout + base) = h;
    *(u16x8*)(loout + base) = l;
  }
  if (bfout) {
    u16x8 ob;
#pragma unroll
    for (int j = 0; j < 4; j++) { ob[j] = f2bf(o0[j]); ob[4 + j] = f2bf(o1[j]); }
    *(u16x8*)(bfout + base) = ob;
  }
}

// ---------------- split-bf16 GEMM (depth-2 prefetch, dbuf LDS, 1 raw barrier/tile) ----
template<int EPI, int PS>
__global__ __launch_bounds__(256) void gemm_split_k(
    const float* __restrict__ A, const unsigned short* __restrict__ Ah,
    const unsigned short* __restrict__ Al, const float* __restrict__ W,
    float* __restrict__ C, int M, int N, int K, int kchunk,
    const float* __restrict__ bias)
{
  __shared__ unsigned short sA[2][2][128 * 32];   // [dbuf][hi/lo]
  __shared__ unsigned short sB[2][2][128 * 32];
  int tid = threadIdx.x;
  int n0 = blockIdx.x * BN, m0 = blockIdx.y * BM;
  int kbase = blockIdx.z * kchunk;
  C += (size_t)blockIdx.z * M * N;
  int lane = tid & 63, wave = tid >> 6;
  int wm = (wave >> 1) * 64, wn = (wave & 1) * 64;
  int lrow = lane & 15, lk = (lane >> 4) * 8;
  int ar = tid >> 1, ac = (tid & 1) * 16;
  int arow = m0 + ar; if (arow >= M) arow = M - 1;
  int wrow = n0 + ar; if (wrow >= N) wrow = N - 1;
  const float* aptr = A + (size_t)arow * K + kbase + ac;            // unused if PS
  const unsigned short* ahp = Ah + (PS ? ((size_t)arow * K + kbase + ac) : 0);
  const unsigned short* alp = Al + (PS ? ((size_t)arow * K + kbase + ac) : 0);
  const float* wptr = W + (size_t)wrow * K + kbase + ac;
  const int NT = kchunk / BK;          // all callers: NT even, >= 4
  f32x4 ra0[4], ra1[4], rw0[4], rw1[4];
  u16x8 rah0[2], ral0[2], rah1[2], ral1[2];
  if constexpr (PS) {
    rah0[0] = *(const u16x8*)(ahp);      rah0[1] = *(const u16x8*)(ahp + 8);
    ral0[0] = *(const u16x8*)(alp);      ral0[1] = *(const u16x8*)(alp + 8);
    rah1[0] = *(const u16x8*)(ahp + BK); rah1[1] = *(const u16x8*)(ahp + BK + 8);
    ral1[0] = *(const u16x8*)(alp + BK); ral1[1] = *(const u16x8*)(alp + BK + 8);
  } else {
#pragma unroll
    for (int q = 0; q < 4; q++) {
      ra0[q] = *(const f32x4*)(aptr + 4 * q);
      ra1[q] = *(const f32x4*)(aptr + BK + 4 * q);
    }
  }
#pragma unroll
  for (int q = 0; q < 4; q++) {
    rw0[q] = *(const f32x4*)(wptr + 4 * q);
    rw1[q] = *(const f32x4*)(wptr + BK + 4 * q);
  }
  f32x4 acc[4][4] = {};
  int c0 = ac, c1 = ac + 8;

#define GS_STEP(PB, TT)                                                      \
  {                                                                          \
    if constexpr (PS) {                                                      \
      *(u16x8*)&sA[PB][0][swz(ar, c0)] = rah##PB[0];                         \
      *(u16x8*)&sA[PB][0][swz(ar, c1)] = rah##PB[1];                         \
      *(u16x8*)&sA[PB][1][swz(ar, c0)] = ral##PB[0];                         \
      *(u16x8*)&sA[PB][1][swz(ar, c1)] = ral##PB[1];                         \
    } else {                                                                 \
      u16x8 h0, l0, h1, l1;                                                  \
      cv_split8(ra##PB[0], ra##PB[1], h0, l0);                               \
      cv_split8(ra##PB[2], ra##PB[3], h1, l1);                               \
      *(u16x8*)&sA[PB][0][swz(ar, c0)] = h0;                                 \
      *(u16x8*)&sA[PB][1][swz(ar, c0)] = l0;                                 \
      *(u16x8*)&sA[PB][0][swz(ar, c1)] = h1;                                 \
      *(u16x8*)&sA[PB][1][swz(ar, c1)] = l1;                                 \
    }                                                                        \
    {                                                                        \
      u16x8 h0, l0, h1, l1;                                                  \
      cv_split8(rw##PB[0], rw##PB[1], h0, l0);                               \
      cv_split8(rw##PB[2], rw##PB[3], h1, l1);                               \
      *(u16x8*)&sB[PB][0][swz(ar, c0)] = h0;                                 \
      *(u16x8*)&sB[PB][1][swz(ar, c0)] = l0;                                 \
      *(u16x8*)&sB[PB][0][swz(ar, c1)] = h1;                                 \
      *(u16x8*)&sB[PB][1][swz(ar, c1)] = l1;                                 \
    }                                                                        \
    if ((TT) + 2 < NT) {                                                     \
      int kk = ((TT) + 2) * BK;                                              \
      if constexpr (PS) {                                                    \
        rah##PB[0] = *(const u16x8*)(ahp + kk);                              \
        rah##PB[1] = *(const u16x8*)(ahp + kk + 8);                          \
        ral##PB[0] = *(const u16x8*)(alp + kk);                              \
        ral##PB[1] = *(const u16x8*)(alp + kk + 8);                          \
      } else {                                                               \
        _Pragma("unroll")                                                    \
        for (int q = 0; q < 4; q++) ra##PB[q] = *(const f32x4*)(aptr + kk + 4 * q); \
      }                                                                      \
      _Pragma("unroll")                                                      \
      for (int q = 0; q < 4; q++) rw##PB[q] = *(const f32x4*)(wptr + kk + 4 * q); \
    }                                                                        \
    pipe_sync();                                                             \
    {                                                                        \
      s16x8 ah[4], al[4];                                                    \
      _Pragma("unroll")                                                      \
      for (int i = 0; i < 4; i++) {                                          \
        int r = wm + i * 16 + lrow;                                          \
        ah[i] = *(const s16x8*)&sA[PB][0][swz(r, lk)];                       \
        al[i] = *(const s16x8*)&sA[PB][1][swz(r, lk)];                       \
      }                                                                      \
      _Pragma("unroll")                                                      \
      for (int ni = 0; ni < 4; ni++) {                                       \
        int r = wn + ni * 16 + lrow;                                         \
        s16x8 bh = *(const s16x8*)&sB[PB][0][swz(r, lk)];                    \
        s16x8 bl = *(const s16x8*)&sB[PB][1][swz(r, lk)];                    \
        _Pragma("unroll")                                                    \
        for (int mi = 0; mi < 4; mi++) {                                     \
          f32x4 tc = acc[mi][ni];                                            \
          tc = mfma16(al[mi], bh, tc);                                       \
          tc = mfma16(ah[mi], bl, tc);                                       \
          tc = mfma16(ah[mi], bh, tc);                                       \
          acc[mi][ni] = tc;                                                  \
        }                                                                    \
      }                                                                      \
    }                                                                        \
  }

  for (int t = 0; t < NT; t += 2) { GS_STEP(0, t) GS_STEP(1, t + 1) }
#undef GS_STEP

  int rb = wm + (lane >> 4) * 4, cb = wn + (lane & 15);
#pragma unroll
  for (int mi = 0; mi < 4; mi++)
#pragma unroll
    for (int ni = 0; ni < 4; ni++) {
      int col = n0 + cb + ni * 16;
      if (col >= N) continue;
#pragma unroll
      for (int j = 0; j < 4; j++) {
        int row = m0 + rb + mi * 16 + j;
        if (row >= M) continue;
        float v = acc[mi][ni][j];
        if (EPI == 1) { v += bias[col]; v = (v > 20.f) ? v : log1pf(expf(v)); }
        C[(size_t)row * N + col] = v;
      }
    }
}

// ---------------- split-K partial reduction ----------------
__global__ void reduce_parts_k(const float* __restrict__ src, float* __restrict__ dst,
                               int len, int parts)
{
  int i = (blockIdx.x * 256 + threadIdx.x) * 4;
  if (i >= len) return;
  f32x4 s = *(const f32x4*)(src + i);
  for (int p = 1; p < parts; p++) s += *(const f32x4*)(src + (size_t)p * len + i);
  *(f32x4*)(dst + i) = s;
}

// ---------------- causal depthwise conv (K=4) + SiLU ----------------
__global__ __launch_bounds__(256) void conv_silu_k(
    const float* __restrict__ xz, const float* __restrict__ cw,
    const float* __restrict__ cb, float* __restrict__ xc)
{
  int idx = blockIdx.x * 256 + threadIdx.x;      // t*4096 + d
  int t = idx >> 12, d = idx & (DI - 1);
  f32x4 w = *(const f32x4*)(cw + d * 4);
  float acc = cb[d];
#pragma unroll
  for (int k = 0; k < 4; k++) {
    int ts = t - 3 + k;
    if (ts >= 0) acc = fmaf(xz[(size_t)ts * 8192 + d], w[k], acc);
  }
  float v = acc / (1.f + __expf(-acc));
  xc[idx] = v;
}

// ---------------- dt/B/C rmsnorms (row of 160 = 128+16+16) ----------------
__global__ void dtbc_norm_k(const float* __restrict__ xdb,
    const float* __restrict__ dtw, const float* __restrict__ bw, const float* __restrict__ cw,
    float* __restrict__ dtr, float* __restrict__ Bm, float* __restrict__ Cm)
{
  int t = blockIdx.x, lane = threadIdx.x;   // 64 threads
  const float* row = xdb + (size_t)t * 160;
  float v1 = row[lane], v2 = row[64 + lane];
  float vb = (lane < 32) ? row[128 + lane] : 0.f;
  float sd = wred64(v1 * v1 + v2 * v2);
  float sb = wred64((lane < 16) ? vb * vb : 0.f);
  float sc = wred64((lane >= 16 && lane < 32) ? vb * vb : 0.f);
  float scd = rsqrtf(sd * (1.f / 128) + 1e-6f);
  dtr[(size_t)t * 128 + lane]      = v1 * scd * dtw[lane];
  dtr[(size_t)t * 128 + 64 + lane] = v2 * scd * dtw[64 + lane];
  if (lane < 16)      Bm[t * 16 + lane]      = vb * rsqrtf(sb * (1.f / 16) + 1e-6f) * bw[lane];
  else if (lane < 32) Cm[t * 16 + lane - 16] = vb * rsqrtf(sc * (1.f / 16) + 1e-6f) * cw[lane - 16];
}

// ---------------- selective scan; y written IN PLACE over xc ----------------
__global__ __launch_bounds__(256) void scan_k(
    const float* __restrict__ dt, float* __restrict__ xcy,
    const float* __restrict__ xz, const float* __restrict__ Bm,
    const float* __restrict__ Cm, const float* __restrict__ A_log,
    const float* __restrict__ Dp)
{
  __shared__ float sdt[64][16], sxc[64][16], sz[64][16], sB[64][16], sC[64][16], sy[64][16];
  int tid = threadIdx.x;
  int dl = tid >> 4, n = tid & 15;
  int d0 = blockIdx.x * 16;
  int d = d0 + dl;
  float a = -__expf(A_log[d * 16 + n]);
  float dpar = Dp[d];
  float h = 0.f;
  for (int t0 = 0; t0 < LL; t0 += 64) {
#pragma unroll
    for (int i = 0; i < 4; i++) {
      int idx = i * 256 + tid;
      int tt = idx >> 4, c = idx & 15;
      int gt = t0 + tt;
      sdt[tt][c] = dt[(size_t)gt * DI + d0 + c];
      sxc[tt][c] = xcy[(size_t)gt * DI + d0 + c];
      sz[tt][c]  = xz[(size_t)gt * 8192 + DI + d0 + c];
      sB[tt][c]  = Bm[gt * 16 + c];
      sC[tt][c]  = Cm[gt * 16 + c];
    }
    __syncthreads();
    for (int tt = 0; tt < 64; tt++) {
      float dtv = sdt[tt][dl];
      float dA = __expf(dtv * a);
      h = h * dA + dtv * sxc[tt][dl] * sB[tt][n];
      float yc = h * sC[tt][n];
      yc += __shfl_xor(yc, 1, 64);
      yc += __shfl_xor(yc, 2, 64);
      yc += __shfl_xor(yc, 4, 64);
      yc += __shfl_xor(yc, 8, 64);
      if (n == 0) {
        float xv = sxc[tt][dl], zv = sz[tt][dl];
        sy[tt][dl] = (yc + xv * dpar) * (zv / (1.f + __expf(-zv)));
      }
    }
    __syncthreads();
#pragma unroll
    for (int i = 0; i < 4; i++) {
      int idx = i * 256 + tid;
      int tt = idx >> 4, c = idx & 15;
      xcy[(size_t)(t0 + tt) * DI + d0 + c] = sy[tt][c];
    }
    __syncthreads();
  }
}

// ---------------- router: logits + softmax + top-2 ----------------
__global__ void router_topk_k(const float* __restrict__ hs2,
                              const float* __restrict__ rw,
                              int* __restrict__ topi, float* __restrict__ topv)
{
  int t = blockIdx.x, lane = threadIdx.x;   // 64 threads
  float acc[NEXP] = {};
  const float* xr = hs2 + (size_t)t * DMODEL;
  for (int i = lane; i < DMODEL; i += 64) {
    float x = xr[i];
#pragma unroll
    for (int e = 0; e < NEXP; e++) acc[e] += x * rw[e * DMODEL + i];
  }
#pragma unroll
  for (int e = 0; e < NEXP; e++) acc[e] = wred64(acc[e]);
  if (lane == 0) {
    float mx = acc[0];
#pragma unroll
    for (int e = 1; e < NEXP; e++) mx = fmaxf(mx, acc[e]);
    float p[NEXP], s = 0.f;
#pragma unroll
    for (int e = 0; e < NEXP; e++) { p[e] = expf(acc[e] - mx); s += p[e]; }
    float inv = 1.f / s;
#pragma unroll
    for (int e = 0; e < NEXP; e++) p[e] *= inv;
    int i0 = 0;
#pragma unroll
    for (int e = 1; e < NEXP; e++) if (p[e] > p[i0]) i0 = e;
    int i1 = (i0 == 0) ? 1 : 0;
#pragma unroll
    for (int e = 0; e < NEXP; e++) if (e != i0 && p[e] > p[i1]) i1 = e;
    topi[2 * t] = i0; topi[2 * t + 1] = i1;
    topv[2 * t] = p[i0]; topv[2 * t + 1] = p[i1];
  }
}

// ---------------- deterministic per-expert token lists + compact tile list ----------
__global__ void build_lists_k(const int* __restrict__ topi, const float* __restrict__ topv,
                              int* __restrict__ tok, float* __restrict__ gate,
                              int* __restrict__ slot, int* __restrict__ cnt,
                              int* __restrict__ offs, int* __restrict__ mt)
{
  int lane = threadIdx.x;   // 64
  int base[NEXP] = {};
  for (int t0 = 0; t0 < LL; t0 += 64) {
    int t = t0 + lane;
    int i0 = topi[2 * t], i1 = topi[2 * t + 1];
    float p0 = topv[2 * t], p1 = topv[2 * t + 1];
    unsigned long long below = (1ull << lane) - 1ull;
#pragma unroll
    for (int e = 0; e < NEXP; e++) {
      unsigned long long m0 = __ballot(i0 == e);
      if (i0 == e) {
        int pos = base[e] + __popcll(m0 & below);
        tok[e * LL + pos] = t; gate[e * LL + pos] = p0; slot[e * LL + pos] = 0;
      }
      base[e] += __popcll(m0);
      unsigned long long m1 = __ballot(i1 == e);
      if (i1 == e) {
        int pos = base[e] + __popcll(m1 & below);
        tok[e * LL + pos] = t; gate[e * LL + pos] = p1; slot[e * LL + pos] = 1;
      }
      base[e] += __popcll(m1);
    }
  }
  if (lane < NEXP) cnt[lane] = base[lane];
  if (lane == 0) {
    int o = 0;
#pragma unroll
    for (int e = 0; e < NEXP; e++) { offs[e] = o; o += base[e]; }
    int f = 0;
#pragma unroll
    for (int e = 0; e < NEXP; e++)
      for (int m0 = 0; m0 < base[e]; m0 += BM) {
        mt[1 + 2 * f] = e; mt[2 + 2 * f] = m0; f++;
      }
    mt[0] = f;
  }
}

// ---------------- MoE phase 1 (BK=64: 256B DRAM runs, compact grid, depth-2) ---------
// LDS 64KB -> 2 blocks/CU. Per iter: stage [128][64] A (bf16) + [64][64] B1,B2
// (fp32->bf16), then 2 MFMA k-steps. NT = 32.
__global__ __launch_bounds__(256, 2) void moe_gemm1_k(
    const unsigned short* __restrict__ hs2b,
    const float* __restrict__ w1, const float* __restrict__ w3,
    unsigned short* __restrict__ act,
    const int* __restrict__ tok, const int* __restrict__ cnt,
    const int* __restrict__ offs, const int* __restrict__ mt)
{
  int zt = blockIdx.z;
  if (zt >= mt[0]) return;
  int e  = mt[1 + 2 * zt];
  int m0 = mt[2 + 2 * zt];
  int ce = cnt[e];
  int n0 = blockIdx.x * 64;
  __shared__ unsigned short sA[2][128 * 64];    // 32 KB
  __shared__ unsigned short sB1[2][64 * 64];    // 16 KB
  __shared__ unsigned short sB2[2][64 * 64];    // 16 KB
  const float* W1 = w1 + (size_t)e * IFF * DMODEL;
  const float* W3 = w3 + (size_t)e * IFF * DMODEL;
  int tid = threadIdx.x;
  int lane = tid & 63, wave = tid >> 6;
  int wm = (wave >> 1) * 64, wn = (wave & 1) * 32;
  int lrow = lane & 15, lk = (lane >> 4) * 8;
  int ar = tid >> 1, ac = (tid & 1) * 32;       // A: 2 thr/row x 64B
  int br = tid >> 2, bc = (tid & 3) * 16;       // B: 4 thr/row x 64B (256B runs)
  bool av = (m0 + ar) < ce;
  const unsigned short* aptr = hs2b + (size_t)(av ? tok[e * LL + m0 + ar] : 0) * DMODEL + ac;
  const float* w1p = W1 + (size_t)(n0 + br) * DMODEL + bc;
  const float* w3p = W3 + (size_t)(n0 + br) * DMODEL + bc;
  u16x8 ua0[4], ua1[4];
  f32x4 w1r0[4], w1r1[4], w3r0[4], w3r1[4];
#pragma unroll
  for (int q = 0; q < 4; q++) {
    ua0[q] = *(const u16x8*)(aptr + 8 * q);
    ua1[q] = *(const u16x8*)(aptr + 64 + 8 * q);
    w1r0[q] = *(const f32x4*)(w1p + 4 * q);
    w1r1[q] = *(const f32x4*)(w1p + 64 + 4 * q);
    w3r0[q] = *(const f32x4*)(w3p + 4 * q);
    w3r1[q] = *(const f32x4*)(w3p + 64 + 4 * q);
  }
  f32x4 acc1[4][2] = {}, acc2[4][2] = {};
  const int NT = DMODEL / 64;   // 32, even

#define G1_STEP(PB, TT)                                                      \
  {                                                                          \
    *(u16x8*)&sA[PB][swz64(ar, ac)]      = ua##PB[0];                        \
    *(u16x8*)&sA[PB][swz64(ar, ac + 8)]  = ua##PB[1];                        \
    *(u16x8*)&sA[PB][swz64(ar, ac + 16)] = ua##PB[2];                        \
    *(u16x8*)&sA[PB][swz64(ar, ac + 24)] = ua##PB[3];                        \
    u16x8 h;                                                                 \
    cv8(w1r##PB[0], w1r##PB[1], h); *(u16x8*)&sB1[PB][swz64(br, bc)]     = h;\
    cv8(w1r##PB[2], w1r##PB[3], h); *(u16x8*)&sB1[PB][swz64(br, bc + 8)] = h;\
    cv8(w3r##PB[0], w3r##PB[1], h); *(u16x8*)&sB2[PB][swz64(br, bc)]     = h;\
    cv8(w3r##PB[2], w3r##PB[3], h); *(u16x8*)&sB2[PB][swz64(br, bc + 8)] = h;\
    if ((TT) + 2 < NT) {                                                     \
      int kk = ((TT) + 2) * 64;                                              \
      _Pragma("unroll")                                                      \
      for (int q = 0; q < 4; q++) {                                          \
        ua##PB[q]  = *(const u16x8*)(aptr + kk + 8 * q);                     \
        w1r##PB[q] = *(const f32x4*)(w1p + kk + 4 * q);                      \
        w3r##PB[q] = *(const f32x4*)(w3p + kk + 4 * q);                      \
      }                                                                      \
    }                                                                        \
    pipe_sync();                                                             \
    _Pragma("unroll")                                                        \
    for (int ks = 0; ks < 2; ks++) {                                         \
      int ko = lk + ks * 32;                                                 \
      s16x8 af[4];                                                           \
      _Pragma("unroll")                                                      \
      for (int i = 0; i < 4; i++)                                            \
        af[i] = *(const s16x8*)&sA[PB][swz64(wm + i * 16 + lrow, ko)];       \
      _Pragma("unroll")                                                      \
      for (int ni = 0; ni < 2; ni++) {                                       \
        int r = wn + ni * 16 + lrow;                                         \
        s16x8 b1 = *(const s16x8*)&sB1[PB][swz64(r, ko)];                    \
        s16x8 b2 = *(const s16x8*)&sB2[PB][swz64(r, ko)];                    \
        _Pragma("unroll")                                                    \
        for (int mi = 0; mi < 4; mi++) acc1[mi][ni] = mfma16(af[mi], b1, acc1[mi][ni]); \
        _Pragma("unroll")                                                    \
        for (int mi = 0; mi < 4; mi++) acc2[mi][ni] = mfma16(af[mi], b2, acc2[mi][ni]); \
      }                                                                      \
    }                                                                        \
  }

  for (int t = 0; t < NT; t += 2) { G1_STEP(0, t) G1_STEP(1, t + 1) }
#undef G1_STEP

  int rb = wm + (lane >> 4) * 4, cb = wn + (lane & 15);
  int obase = offs[e];
#pragma unroll
  for (int mi = 0; mi < 4; mi++)
#pragma unroll
    for (int j = 0; j < 4; j++) {
      int row = m0 + rb + mi * 16 + j;
      if (row >= ce) continue;
#pragma unroll
      for (int ni = 0; ni < 2; ni++) {
        int col = n0 + cb + ni * 16;
        float g = acc1[mi][ni][j], u = acc2[mi][ni][j];
        float aval = (g / (1.f + __expf(-g))) * u;
        act[(size_t)(obase + row) * IFF + col] = f2bf(aval);
      }
    }
}

// ---------------- MoE phase 2 (BK=64, compact grid, K-split, depth-2) ----------------
// LDS 48KB -> 3 blocks/CU. NT = 44.
__global__ __launch_bounds__(256, 3) void moe_gemm2_k(
    const unsigned short* __restrict__ act, const float* __restrict__ w2,
    float* __restrict__ g2p,
    const int* __restrict__ tok, const float* __restrict__ gate,
    const int* __restrict__ slot, const int* __restrict__ cnt,
    const int* __restrict__ offs, const int* __restrict__ mt)
{
  int zt = blockIdx.z;
  if (zt >= mt[0]) return;
  int e  = mt[1 + 2 * zt];
  int m0 = mt[2 + 2 * zt];
  int ce = cnt[e];
  int part = blockIdx.y;
  int n0 = blockIdx.x * 64;
  int kbase = part * G2CHUNK;
  const int NT = G2CHUNK / 64;   // 44, even
  __shared__ unsigned short sA[2][128 * 64];    // 32 KB
  __shared__ unsigned short sB[2][64 * 64];     // 16 KB
  const float* W = w2 + (size_t)e * DMODEL * IFF;
  int obase = offs[e];
  int tid = threadIdx.x;
  int lane = tid & 63, wave = tid >> 6;
  int wm = (wave >> 1) * 64, wn = (wave & 1) * 32;
  int lrow = lane & 15, lk = (lane >> 4) * 8;
  int ar = tid >> 1, ac = (tid & 1) * 32;
  int br = tid >> 2, bc = (tid & 3) * 16;
  bool av = (m0 + ar) < ce;
  const unsigned short* aptr = act + (size_t)(obase + (av ? (m0 + ar) : 0)) * IFF + kbase + ac;
  const float* wp = W + (size_t)(n0 + br) * IFF + kbase + bc;
  u16x8 ua0[4], ua1[4];
  f32x4 rw0[4], rw1[4];
#pragma unroll
  for (int q = 0; q < 4; q++) {
    ua0[q] = *(const u16x8*)(aptr + 8 * q);
    ua1[q] = *(const u16x8*)(aptr + 64 + 8 * q);
    rw0[q] = *(const f32x4*)(wp + 4 * q);
    rw1[q] = *(const f32x4*)(wp + 64 + 4 * q);
  }
  f32x4 acc[4][2] = {};

#define G2_STEP(PB, TT)                                                      \
  {                                                                          \
    *(u16x8*)&sA[PB][swz64(ar, ac)]      = ua##PB[0];                        \
    *(u16x8*)&sA[PB][swz64(ar, ac + 8)]  = ua##PB[1];                        \
    *(u16x8*)&sA[PB][swz64(ar, ac + 16)] = ua##PB[2];                        \
    *(u16x8*)&sA[PB][swz64(ar, ac + 24)] = ua##PB[3];                        \
    u16x8 h;                                                                 \
    cv8(rw##PB[0], rw##PB[1], h); *(u16x8*)&sB[PB][swz64(br, bc)]     = h;   \
    cv8(rw##PB[2], rw##PB[3], h); *(u16x8*)&sB[PB][swz64(br, bc + 8)] = h;   \
    if ((TT) + 2 < NT) {                                                     \
      int kk = ((TT) + 2) * 64;                                              \
      _Pragma("unroll")                                                      \
      for (int q = 0; q < 4; q++) {                                          \
        ua##PB[q] = *(const u16x8*)(aptr + kk + 8 * q);                      \
        rw##PB[q] = *(const f32x4*)(wp + kk + 4 * q);                        \
      }                                                                      \
    }                                                                        \
    pipe_sync();                                                             \
    _Pragma("unroll")                                                        \
    for (int ks = 0; ks < 2; ks++) {                                         \
      int ko = lk + ks * 32;                                                 \
      s16x8 af[4];                                                           \
      _Pragma("unroll")                                                      \
      for (int i = 0; i < 4; i++)                                            \
        af[i] = *(const s16x8*)&sA[PB][swz64(wm + i * 16 + lrow, ko)];       \
      _Pragma("unroll")                                                      \
      for (int ni = 0; ni < 2; ni++) {                                       \
        s16x8 b = *(const s16x8*)&sB[PB][swz64(wn + ni * 16 + lrow, ko)];    \
        _Pragma("unroll")                                                    \
        for (int mi = 0; mi < 4; mi++) acc[mi][ni] = mfma16(af[mi], b, acc[mi][ni]); \
      }                                                                      \
    }                                                                        \
  }

  for (int t = 0; t < NT; t += 2) { G2_STEP(0, t) G2_STEP(1, t + 1) }
#undef G2_STEP

  int rb = wm + (lane >> 4) * 4, cb = wn + (lane & 15);
#pragma unroll
  for (int mi = 0; mi < 4; mi++)
#pragma unroll
    for (int j = 0; j < 4; j++) {
      int row = m0 + rb + mi * 16 + j;
      if (row >= ce) continue;
      int t = tok[e * LL + row];
      float g = gate[e * LL + row];
      int s = slot[e * LL + row];
      float* dst = g2p + ((size_t)(part * 2 + s) * LL + t) * DMODEL + n0 + cb;
#pragma unroll
      for (int ni = 0; ni < 2; ni++) dst[ni * 16] = acc[mi][ni][j] * g;
    }
}

// ---------------- combine the (part,slot) planes ----------------
__global__ void moe_combine_k(const float* __restrict__ ys, float* __restrict__ out) {
  size_t i = ((size_t)blockIdx.x * 256 + threadIdx.x) * 4;
  f32x4 s = *(const f32x4*)(ys + i);
#pragma unroll
  for (int p = 1; p < 2 * G2PARTS; p++)
    s += *(const f32x4*)(ys + (size_t)p * LL * DMODEL + i);
  *(f32x4*)(out + i) = s;
}

// ---------------- launch ----------------
extern "C" void kernel_launch(void* const* d_in, const int* in_sizes, int n_in,
                              void* d_out, int out_size, void* d_ws, size_t ws_size,
                              hipStream_t stream)
{
  (void)in_sizes; (void)n_in; (void)out_size; (void)ws_size;
  const float* hidden     = (const float*)d_in[0];
  const float* ln_in_w    = (const float*)d_in[1];
  const float* in_proj_w  = (const float*)d_in[2];
  const float* conv_w     = (const float*)d_in[3];
  const float* conv_b     = (const float*)d_in[4];
  const float* x_proj_w   = (const float*)d_in[5];
  const float* dt_ln_w    = (const float*)d_in[6];
  const float* b_ln_w     = (const float*)d_in[7];
  const float* c_ln_w     = (const float*)d_in[8];
  const float* dt_proj_w  = (const float*)d_in[9];
  const float* dt_proj_b  = (const float*)d_in[10];
  const float* A_log      = (const float*)d_in[11];
  const float* D_param    = (const float*)d_in[12];
  const float* out_proj_w = (const float*)d_in[13];
  const float* ln_ff_w    = (const float*)d_in[14];
  const float* router_w   = (const float*)d_in[15];
  const float* w1         = (const float*)d_in[16];
  const float* w3         = (const float*)d_in[17];
  const float* w2         = (const float*)d_in[18];
  float* moe_out  = (float*)d_out;
  float* residual = (float*)d_out + (size_t)LL * DMODEL;

  char* p = (char*)d_ws;
  auto alloc = [&](size_t bytes) { char* r = p; p += (bytes + 255) & ~(size_t)255; return r; };
  unsigned short* hs_hi  = (unsigned short*)alloc((size_t)LL * DMODEL * 2);
  unsigned short* hs_lo  = (unsigned short*)alloc((size_t)LL * DMODEL * 2);
  float* xz              = (float*)alloc((size_t)LL * 2 * DI * 4);   // aliased: out_parts, act_buf
  float* xc              = (float*)alloc((size_t)LL * DI * 4);       // conv out; scan writes y in place
  float* xdb             = (float*)alloc((size_t)LL * 160 * 4);
  float* dtr             = (float*)alloc((size_t)LL * 128 * 4);
  float* Bm              = (float*)alloc((size_t)LL * 16 * 4);
  float* Cm              = (float*)alloc((size_t)LL * 16 * 4);
  float* dt_full         = (float*)alloc((size_t)LL * DI * 4);       // aliased: xdb_parts
  float* mamba_out       = (float*)alloc((size_t)LL * DMODEL * 4);
  float* hs2_f           = (float*)alloc((size_t)LL * DMODEL * 4);
  unsigned short* hs2_bf = (unsigned short*)alloc((size_t)LL * DMODEL * 2);
  int* topi              = (int*)alloc(LL * 2 * 4);
  float* topv            = (float*)alloc(LL * 2 * 4);
  int* tok               = (int*)alloc(NEXP * LL * 4);
  float* gate            = (float*)alloc(NEXP * LL * 4);
  int* slot              = (int*)alloc(NEXP * LL * 4);
  int* cnt               = (int*)alloc(256);
  int* offs              = (int*)alloc(256);
  int* mt                = (int*)alloc((1 + 2 * 64) * 4);   // tile list: count + (e,m0) pairs
  // aliases (lifetimes strictly ordered by stream order):
  float* xdb_parts        = dt_full;               // 16 x 0.655 MB = 10.5 <= 16.78
  float* out_parts        = xz;                    // 4 x 8.39 MB = 33.55 (xz dead after scan)
  unsigned short* act_buf = (unsigned short*)xz;   // 23.07 MB (after out-reduce)
  float* g2parts          = (float*)((char*)act_buf + (size_t)2 * LL * IFF * 2); // 33.55 MB
  //   g2parts spans [23.1, 56.6) MB rel xz: overlaps xz-tail/xc/xdb/dtr — all dead
  //   by moe_gemm2 time; hs2_bf / tok / gate / slot / cnt / offs / mt live beyond it.

  rmsnorm_k<<<LL, 256, 0, stream>>>(hidden, ln_in_w, nullptr, nullptr, nullptr, hs_hi, hs_lo, nullptr);
  gemm_split_k<0, 1><<<dim3(64, 8, 1), 256, 0, stream>>>(nullptr, hs_hi, hs_lo, in_proj_w, xz, LL, 2 * DI, DMODEL, DMODEL, nullptr);
  conv_silu_k<<<(LL * DI) / 256, 256, 0, stream>>>(xz, conv_w, conv_b, xc);
  gemm_split_k<0, 0><<<dim3(2, 8, 16), 256, 0, stream>>>(xc, nullptr, nullptr, x_proj_w, xdb_parts, LL, 160, DI, DI / 16, nullptr);
  reduce_parts_k<<<(LL * 160) / 1024, 256, 0, stream>>>(xdb_parts, xdb, LL * 160, 16);
  dtbc_norm_k<<<LL, 64, 0, stream>>>(xdb, dt_ln_w, b_ln_w, c_ln_w, dtr, Bm, Cm);
  gemm_split_k<1, 0><<<dim3(32, 8, 1), 256, 0, stream>>>(dtr, nullptr, nullptr, dt_proj_w, dt_full, LL, DI, RDT, RDT, dt_proj_b);
  scan_k<<<DI / 16, 256, 0, stream>>>(dt_full, xc, xz, Bm, Cm, A_log, D_param);
  gemm_split_k<0, 0><<<dim3(16, 8, 4), 256, 0, stream>>>(xc, nullptr, nullptr, out_proj_w, out_parts, LL, DMODEL, DI, DI / 4, nullptr);
  reduce_parts_k<<<(LL * DMODEL) / 1024, 256, 0, stream>>>(out_parts, mamba_out, LL * DMODEL, 4);
  rmsnorm_k<<<LL, 256, 0, stream>>>(mamba_out, ln_ff_w, hidden, residual, hs2_f, nullptr, nullptr, hs2_bf);
  router_topk_k<<<LL, 64, 0, stream>>>(hs2_f, router_w, topi, topv);
  build_lists_k<<<1, 64, 0, stream>>>(topi, topv, tok, gate, slot, cnt, offs, mt);
  moe_gemm1_k<<<dim3(88, 1, MAXTILES), 256, 0, stream>>>(hs2_bf, w1, w3, act_buf, tok, cnt, offs, mt);
  moe_gemm2_k<<<dim3(32, G2PARTS, MAXTILES), 256, 0, stream>>>(act_buf, w2, g2parts, tok, gate, slot, cnt, offs, mt);
  moe_combine_k<<<(LL * DMODEL) / (256 * 4), 256, 0, stream>>>(g2parts, moe_out);
}

// Round 10
// 905.634 us; speedup vs baseline: 1.1925x; 1.1141x over previous
//
#include <hip/hip_runtime.h>
#include <hip/hip_bf16.h>
#include <stdint.h>

// ---------------- types / helpers ----------------
typedef __attribute__((ext_vector_type(4))) float f32x4;
typedef __attribute__((ext_vector_type(8))) short s16x8;          // MFMA bf16 frag
typedef __attribute__((ext_vector_type(8))) unsigned short u16x8;

#define LL 1024
#define DMODEL 2048
#define DI 4096
#define NSTATE 16
#define RDT 128
#define NEXP 8
#define IFF 5632

#define BM 128
#define BN 128
#define BK 32
#define G2CHUNK 2816   // moe_gemm2 K-split chunk (2 parts; BK=64 -> NT=44 even)
#define G2PARTS 2
#define MAXTILES 23    // worst-case sum over experts of ceil(ce/128), sum ce = 2048

__device__ inline unsigned short f2bf(float f) {            // fp32 -> bf16 RNE (bit ops)
  unsigned int u = __builtin_bit_cast(unsigned int, f);
  u += 0x7fffu + ((u >> 16) & 1u);
  return (unsigned short)(u >> 16);
}
__device__ inline unsigned short cvbf(float f) {            // compiler path (v_cvt capable)
  return __builtin_bit_cast(unsigned short, __float2bfloat16(f));
}
__device__ inline float upbf(unsigned short h) {
  return __builtin_bit_cast(float, (unsigned int)h << 16);
}
__device__ inline float wred64(float v) {
#pragma unroll
  for (int m = 32; m; m >>= 1) v += __shfl_xor(v, m, 64);
  return v;
}
__device__ inline f32x4 mfma16(s16x8 a, s16x8 b, f32x4 c) {
  return __builtin_amdgcn_mfma_f32_16x16x32_bf16(a, b, c, 0, 0, 0);
}
// LDS tile index, 32-elem rows (mamba GEMMs): XOR-swizzle 8-elem granules
__device__ inline int swz(int row, int chunk) {
  return row * 32 + (chunk ^ ((row & 3) << 3));
}
// LDS tile index, 64-elem rows (MoE GEMMs, BK=64)
__device__ inline int swz64(int row, int chunk) {
  return row * 64 + (chunk ^ ((row & 7) << 3));
}
__device__ inline void cv8(f32x4 a, f32x4 b, u16x8& h) {
#pragma unroll
  for (int j = 0; j < 4; j++) { h[j] = cvbf(a[j]); h[4 + j] = cvbf(b[j]); }
}
__device__ inline void cv_split8(f32x4 a, f32x4 b, u16x8& h, u16x8& l) {
#pragma unroll
  for (int j = 0; j < 4; j++) {
    unsigned short hh = cvbf(a[j]); h[j] = hh; l[j] = cvbf(a[j] - upbf(hh));
    unsigned short hb = cvbf(b[j]); h[4 + j] = hb; l[4 + j] = cvbf(b[j] - upbf(hb));
  }
}
// Barrier WITHOUT the compiler's vmcnt(0) drain (T4-minimum).
__device__ inline void pipe_sync() {
  __builtin_amdgcn_sched_barrier(0);
  asm volatile("s_waitcnt lgkmcnt(0)" ::: "memory");
  __builtin_amdgcn_sched_barrier(0);
  __builtin_amdgcn_s_barrier();
  __builtin_amdgcn_sched_barrier(0);
}

// ---------------- RMSNorm (optionally fused residual-add) ----------------
__global__ __launch_bounds__(256) void rmsnorm_k(
    const float* __restrict__ x, const float* __restrict__ w,
    const float* __restrict__ addin, float* __restrict__ resout,
    float* __restrict__ f32out, unsigned short* __restrict__ hiout,
    unsigned short* __restrict__ loout, unsigned short* __restrict__ bfout)
{
  int t = blockIdx.x, tid = threadIdx.x;
  size_t base = (size_t)t * DMODEL + tid * 8;
  f32x4 v0 = *(const f32x4*)(x + base);
  f32x4 v1 = *(const f32x4*)(x + base + 4);
  if (addin) {
    v0 += *(const f32x4*)(addin + base);
    v1 += *(const f32x4*)(addin + base + 4);
  }
  float ss = 0.f;
#pragma unroll
  for (int j = 0; j < 4; j++) ss += v0[j]*v0[j] + v1[j]*v1[j];
  ss = wred64(ss);
  __shared__ float sred[4];
  if ((tid & 63) == 0) sred[tid >> 6] = ss;
  __syncthreads();
  ss = sred[0] + sred[1] + sred[2] + sred[3];
  float sc = rsqrtf(ss * (1.f / DMODEL) + 1e-6f);
  if (resout) {
    *(f32x4*)(resout + base) = v0;
    *(f32x4*)(resout + base + 4) = v1;
  }
  f32x4 w0 = *(const f32x4*)(w + tid * 8);
  f32x4 w1 = *(const f32x4*)(w + tid * 8 + 4);
  f32x4 o0 = v0 * sc * w0, o1 = v1 * sc * w1;
  if (f32out) {
    *(f32x4*)(f32out + base) = o0;
    *(f32x4*)(f32out + base + 4) = o1;
  }
  if (hiout) {
    u16x8 h, l;
    cv_split8(o0, o1, h, l);
    *(u16x8*)(hiout + base) = h;
    *(u16x8*)(loout + base) = l;
  }
  if (bfout) {
    u16x8 ob;
#pragma unroll
    for (int j = 0; j < 4; j++) { ob[j] = f2bf(o0[j]); ob[4 + j] = f2bf(o1[j]); }
    *(u16x8*)(bfout + base) = ob;
  }
}

// ---------------- split-bf16 GEMM (depth-2 prefetch, dbuf LDS, 1 raw barrier/tile) ----
template<int EPI, int PS>
__global__ __launch_bounds__(256) void gemm_split_k(
    const float* __restrict__ A, const unsigned short* __restrict__ Ah,
    const unsigned short* __restrict__ Al, const float* __restrict__ W,
    float* __restrict__ C, int M, int N, int K, int kchunk,
    const float* __restrict__ bias)
{
  __shared__ unsigned short sA[2][2][128 * 32];   // [dbuf][hi/lo]
  __shared__ unsigned short sB[2][2][128 * 32];
  int tid = threadIdx.x;
  int n0 = blockIdx.x * BN, m0 = blockIdx.y * BM;
  int kbase = blockIdx.z * kchunk;
  C += (size_t)blockIdx.z * M * N;
  int lane = tid & 63, wave = tid >> 6;
  int wm = (wave >> 1) * 64, wn = (wave & 1) * 64;
  int lrow = lane & 15, lk = (lane >> 4) * 8;
  int ar = tid >> 1, ac = (tid & 1) * 16;
  int arow = m0 + ar; if (arow >= M) arow = M - 1;
  int wrow = n0 + ar; if (wrow >= N) wrow = N - 1;
  const float* aptr = A + (size_t)arow * K + kbase + ac;            // unused if PS
  const unsigned short* ahp = Ah + (PS ? ((size_t)arow * K + kbase + ac) : 0);
  const unsigned short* alp = Al + (PS ? ((size_t)arow * K + kbase + ac) : 0);
  const float* wptr = W + (size_t)wrow * K + kbase + ac;
  const int NT = kchunk / BK;          // all callers: NT even, >= 4
  f32x4 ra0[4], ra1[4], rw0[4], rw1[4];
  u16x8 rah0[2], ral0[2], rah1[2], ral1[2];
  if constexpr (PS) {
    rah0[0] = *(const u16x8*)(ahp);      rah0[1] = *(const u16x8*)(ahp + 8);
    ral0[0] = *(const u16x8*)(alp);      ral0[1] = *(const u16x8*)(alp + 8);
    rah1[0] = *(const u16x8*)(ahp + BK); rah1[1] = *(const u16x8*)(ahp + BK + 8);
    ral1[0] = *(const u16x8*)(alp + BK); ral1[1] = *(const u16x8*)(alp + BK + 8);
  } else {
#pragma unroll
    for (int q = 0; q < 4; q++) {
      ra0[q] = *(const f32x4*)(aptr + 4 * q);
      ra1[q] = *(const f32x4*)(aptr + BK + 4 * q);
    }
  }
#pragma unroll
  for (int q = 0; q < 4; q++) {
    rw0[q] = *(const f32x4*)(wptr + 4 * q);
    rw1[q] = *(const f32x4*)(wptr + BK + 4 * q);
  }
  f32x4 acc[4][4] = {};
  int c0 = ac, c1 = ac + 8;

#define GS_STEP(PB, TT)                                                      \
  {                                                                          \
    if constexpr (PS) {                                                      \
      *(u16x8*)&sA[PB][0][swz(ar, c0)] = rah##PB[0];                         \
      *(u16x8*)&sA[PB][0][swz(ar, c1)] = rah##PB[1];                         \
      *(u16x8*)&sA[PB][1][swz(ar, c0)] = ral##PB[0];                         \
      *(u16x8*)&sA[PB][1][swz(ar, c1)] = ral##PB[1];                         \
    } else {                                                                 \
      u16x8 h0, l0, h1, l1;                                                  \
      cv_split8(ra##PB[0], ra##PB[1], h0, l0);                               \
      cv_split8(ra##PB[2], ra##PB[3], h1, l1);                               \
      *(u16x8*)&sA[PB][0][swz(ar, c0)] = h0;                                 \
      *(u16x8*)&sA[PB][1][swz(ar, c0)] = l0;                                 \
      *(u16x8*)&sA[PB][0][swz(ar, c1)] = h1;                                 \
      *(u16x8*)&sA[PB][1][swz(ar, c1)] = l1;                                 \
    }                                                                        \
    {                                                                        \
      u16x8 h0, l0, h1, l1;                                                  \
      cv_split8(rw##PB[0], rw##PB[1], h0, l0);                               \
      cv_split8(rw##PB[2], rw##PB[3], h1, l1);                               \
      *(u16x8*)&sB[PB][0][swz(ar, c0)] = h0;                                 \
      *(u16x8*)&sB[PB][1][swz(ar, c0)] = l0;                                 \
      *(u16x8*)&sB[PB][0][swz(ar, c1)] = h1;                                 \
      *(u16x8*)&sB[PB][1][swz(ar, c1)] = l1;                                 \
    }                                                                        \
    if ((TT) + 2 < NT) {                                                     \
      int kk = ((TT) + 2) * BK;                                              \
      if constexpr (PS) {                                                    \
        rah##PB[0] = *(const u16x8*)(ahp + kk);                              \
        rah##PB[1] = *(const u16x8*)(ahp + kk + 8);                          \
        ral##PB[0] = *(const u16x8*)(alp + kk);                              \
        ral##PB[1] = *(const u16x8*)(alp + kk + 8);                          \
      } else {                                                               \
        _Pragma("unroll")                                                    \
        for (int q = 0; q < 4; q++) ra##PB[q] = *(const f32x4*)(aptr + kk + 4 * q); \
      }                                                                      \
      _Pragma("unroll")                                                      \
      for (int q = 0; q < 4; q++) rw##PB[q] = *(const f32x4*)(wptr + kk + 4 * q); \
    }                                                                        \
    pipe_sync();                                                             \
    {                                                                        \
      s16x8 ah[4], al[4];                                                    \
      _Pragma("unroll")                                                      \
      for (int i = 0; i < 4; i++) {                                          \
        int r = wm + i * 16 + lrow;                                          \
        ah[i] = *(const s16x8*)&sA[PB][0][swz(r, lk)];                       \
        al[i] = *(const s16x8*)&sA[PB][1][swz(r, lk)];                       \
      }                                                                      \
      _Pragma("unroll")                                                      \
      for (int ni = 0; ni < 4; ni++) {                                       \
        int r = wn + ni * 16 + lrow;                                         \
        s16x8 bh = *(const s16x8*)&sB[PB][0][swz(r, lk)];                    \
        s16x8 bl = *(const s16x8*)&sB[PB][1][swz(r, lk)];                    \
        _Pragma("unroll")                                                    \
        for (int mi = 0; mi < 4; mi++) {                                     \
          f32x4 tc = acc[mi][ni];                                            \
          tc = mfma16(al[mi], bh, tc);                                       \
          tc = mfma16(ah[mi], bl, tc);                                       \
          tc = mfma16(ah[mi], bh, tc);                                       \
          acc[mi][ni] = tc;                                                  \
        }                                                                    \
      }                                                                      \
    }                                                                        \
  }

  for (int t = 0; t < NT; t += 2) { GS_STEP(0, t) GS_STEP(1, t + 1) }
#undef GS_STEP

  int rb = wm + (lane >> 4) * 4, cb = wn + (lane & 15);
#pragma unroll
  for (int mi = 0; mi < 4; mi++)
#pragma unroll
    for (int ni = 0; ni < 4; ni++) {
      int col = n0 + cb + ni * 16;
      if (col >= N) continue;
#pragma unroll
      for (int j = 0; j < 4; j++) {
        int row = m0 + rb + mi * 16 + j;
        if (row >= M) continue;
        float v = acc[mi][ni][j];
        if (EPI == 1) { v += bias[col]; v = (v > 20.f) ? v : log1pf(expf(v)); }
        C[(size_t)row * N + col] = v;
      }
    }
}

// ---------------- split-K partial reduction ----------------
__global__ void reduce_parts_k(const float* __restrict__ src, float* __restrict__ dst,
                               int len, int parts)
{
  int i = (blockIdx.x * 256 + threadIdx.x) * 4;
  if (i >= len) return;
  f32x4 s = *(const f32x4*)(src + i);
  for (int p = 1; p < parts; p++) s += *(const f32x4*)(src + (size_t)p * len + i);
  *(f32x4*)(dst + i) = s;
}

// ---------------- causal depthwise conv (K=4) + SiLU ----------------
__global__ __launch_bounds__(256) void conv_silu_k(
    const float* __restrict__ xz, const float* __restrict__ cw,
    const float* __restrict__ cb, float* __restrict__ xc)
{
  int idx = blockIdx.x * 256 + threadIdx.x;      // t*4096 + d
  int t = idx >> 12, d = idx & (DI - 1);
  f32x4 w = *(const f32x4*)(cw + d * 4);
  float acc = cb[d];
#pragma unroll
  for (int k = 0; k < 4; k++) {
    int ts = t - 3 + k;
    if (ts >= 0) acc = fmaf(xz[(size_t)ts * 8192 + d], w[k], acc);
  }
  float v = acc / (1.f + __expf(-acc));
  xc[idx] = v;
}

// ---------------- dt/B/C rmsnorms (row of 160 = 128+16+16) ----------------
__global__ void dtbc_norm_k(const float* __restrict__ xdb,
    const float* __restrict__ dtw, const float* __restrict__ bw, const float* __restrict__ cw,
    float* __restrict__ dtr, float* __restrict__ Bm, float* __restrict__ Cm)
{
  int t = blockIdx.x, lane = threadIdx.x;   // 64 threads
  const float* row = xdb + (size_t)t * 160;
  float v1 = row[lane], v2 = row[64 + lane];
  float vb = (lane < 32) ? row[128 + lane] : 0.f;
  float sd = wred64(v1 * v1 + v2 * v2);
  float sb = wred64((lane < 16) ? vb * vb : 0.f);
  float sc = wred64((lane >= 16 && lane < 32) ? vb * vb : 0.f);
  float scd = rsqrtf(sd * (1.f / 128) + 1e-6f);
  dtr[(size_t)t * 128 + lane]      = v1 * scd * dtw[lane];
  dtr[(size_t)t * 128 + 64 + lane] = v2 * scd * dtw[64 + lane];
  if (lane < 16)      Bm[t * 16 + lane]      = vb * rsqrtf(sb * (1.f / 16) + 1e-6f) * bw[lane];
  else if (lane < 32) Cm[t * 16 + lane - 16] = vb * rsqrtf(sc * (1.f / 16) + 1e-6f) * cw[lane - 16];
}

// ---------------- selective scan; y written IN PLACE over xc ----------------
// 8-way ILP inner loop: the h-recurrence is a cheap FMA chain; the 4-level
// shfl_xor reduce (LDS-pipe, ~35cy/level) is the latency bottleneck at
// 1 wave/SIMD occupancy. Batching 8 timesteps interleaves 8 independent
// reduce chains -> latency amortized 8x. Reduce order per value unchanged
// (bit-identical numerics).
__global__ __launch_bounds__(256) void scan_k(
    const float* __restrict__ dt, float* __restrict__ xcy,
    const float* __restrict__ xz, const float* __restrict__ Bm,
    const float* __restrict__ Cm, const float* __restrict__ A_log,
    const float* __restrict__ Dp)
{
  __shared__ float sdt[64][16], sxc[64][16], sz[64][16], sB[64][16], sC[64][16], sy[64][16];
  int tid = threadIdx.x;
  int dl = tid >> 4, n = tid & 15;
  int d0 = blockIdx.x * 16;
  int d = d0 + dl;
  float a = -__expf(A_log[d * 16 + n]);
  float dpar = Dp[d];
  float h = 0.f;
  for (int t0 = 0; t0 < LL; t0 += 64) {
#pragma unroll
    for (int i = 0; i < 4; i++) {
      int idx = i * 256 + tid;
      int tt = idx >> 4, c = idx & 15;
      int gt = t0 + tt;
      sdt[tt][c] = dt[(size_t)gt * DI + d0 + c];
      sxc[tt][c] = xcy[(size_t)gt * DI + d0 + c];
      sz[tt][c]  = xz[(size_t)gt * 8192 + DI + d0 + c];
      sB[tt][c]  = Bm[gt * 16 + c];
      sC[tt][c]  = Cm[gt * 16 + c];
    }
    __syncthreads();
    for (int tg = 0; tg < 64; tg += 8) {
      float yv[8];
#pragma unroll
      for (int u = 0; u < 8; u++) {
        int tt = tg + u;
        float dtv = sdt[tt][dl];
        float dA = __expf(dtv * a);
        h = h * dA + dtv * sxc[tt][dl] * sB[tt][n];
        yv[u] = h * sC[tt][n];
      }
#pragma unroll
      for (int u = 0; u < 8; u++) yv[u] += __shfl_xor(yv[u], 1, 64);
#pragma unroll
      for (int u = 0; u < 8; u++) yv[u] += __shfl_xor(yv[u], 2, 64);
#pragma unroll
      for (int u = 0; u < 8; u++) yv[u] += __shfl_xor(yv[u], 4, 64);
#pragma unroll
      for (int u = 0; u < 8; u++) yv[u] += __shfl_xor(yv[u], 8, 64);
      if (n == 0) {
#pragma unroll
        for (int u = 0; u < 8; u++) {
          int tt = tg + u;
          float xv = sxc[tt][dl], zv = sz[tt][dl];
          sy[tt][dl] = (yv[u] + xv * dpar) * (zv / (1.f + __expf(-zv)));
        }
      }
    }
    __syncthreads();
#pragma unroll
    for (int i = 0; i < 4; i++) {
      int idx = i * 256 + tid;
      int tt = idx >> 4, c = idx & 15;
      xcy[(size_t)(t0 + tt) * DI + d0 + c] = sy[tt][c];
    }
    __syncthreads();
  }
}

// ---------------- router: logits + softmax + top-2 ----------------
__global__ void router_topk_k(const float* __restrict__ hs2,
                              const float* __restrict__ rw,
                              int* __restrict__ topi, float* __restrict__ topv)
{
  int t = blockIdx.x, lane = threadIdx.x;   // 64 threads
  float acc[NEXP] = {};
  const float* xr = hs2 + (size_t)t * DMODEL;
  for (int i = lane; i < DMODEL; i += 64) {
    float x = xr[i];
#pragma unroll
    for (int e = 0; e < NEXP; e++) acc[e] += x * rw[e * DMODEL + i];
  }
#pragma unroll
  for (int e = 0; e < NEXP; e++) acc[e] = wred64(acc[e]);
  if (lane == 0) {
    float mx = acc[0];
#pragma unroll
    for (int e = 1; e < NEXP; e++) mx = fmaxf(mx, acc[e]);
    float p[NEXP], s = 0.f;
#pragma unroll
    for (int e = 0; e < NEXP; e++) { p[e] = expf(acc[e] - mx); s += p[e]; }
    float inv = 1.f / s;
#pragma unroll
    for (int e = 0; e < NEXP; e++) p[e] *= inv;
    int i0 = 0;
#pragma unroll
    for (int e = 1; e < NEXP; e++) if (p[e] > p[i0]) i0 = e;
    int i1 = (i0 == 0) ? 1 : 0;
#pragma unroll
    for (int e = 0; e < NEXP; e++) if (e != i0 && p[e] > p[i1]) i1 = e;
    topi[2 * t] = i0; topi[2 * t + 1] = i1;
    topv[2 * t] = p[i0]; topv[2 * t + 1] = p[i1];
  }
}

// ---------------- deterministic per-expert token lists + compact tile list ----------
__global__ void build_lists_k(const int* __restrict__ topi, const float* __restrict__ topv,
                              int* __restrict__ tok, float* __restrict__ gate,
                              int* __restrict__ slot, int* __restrict__ cnt,
                              int* __restrict__ offs, int* __restrict__ mt)
{
  int lane = threadIdx.x;   // 64
  int base[NEXP] = {};
  for (int t0 = 0; t0 < LL; t0 += 64) {
    int t = t0 + lane;
    int i0 = topi[2 * t], i1 = topi[2 * t + 1];
    float p0 = topv[2 * t], p1 = topv[2 * t + 1];
    unsigned long long below = (1ull << lane) - 1ull;
#pragma unroll
    for (int e = 0; e < NEXP; e++) {
      unsigned long long m0 = __ballot(i0 == e);
      if (i0 == e) {
        int pos = base[e] + __popcll(m0 & below);
        tok[e * LL + pos] = t; gate[e * LL + pos] = p0; slot[e * LL + pos] = 0;
      }
      base[e] += __popcll(m0);
      unsigned long long m1 = __ballot(i1 == e);
      if (i1 == e) {
        int pos = base[e] + __popcll(m1 & below);
        tok[e * LL + pos] = t; gate[e * LL + pos] = p1; slot[e * LL + pos] = 1;
      }
      base[e] += __popcll(m1);
    }
  }
  if (lane < NEXP) cnt[lane] = base[lane];
  if (lane == 0) {
    int o = 0;
#pragma unroll
    for (int e = 0; e < NEXP; e++) { offs[e] = o; o += base[e]; }
    int f = 0;
#pragma unroll
    for (int e = 0; e < NEXP; e++)
      for (int m0 = 0; m0 < base[e]; m0 += BM) {
        mt[1 + 2 * f] = e; mt[2 + 2 * f] = m0; f++;
      }
    mt[0] = f;
  }
}

// ---------------- MoE phase 1 (BK=64: 256B DRAM runs, compact grid, depth-2) ---------
__global__ __launch_bounds__(256, 2) void moe_gemm1_k(
    const unsigned short* __restrict__ hs2b,
    const float* __restrict__ w1, const float* __restrict__ w3,
    unsigned short* __restrict__ act,
    const int* __restrict__ tok, const int* __restrict__ cnt,
    const int* __restrict__ offs, const int* __restrict__ mt)
{
  int zt = blockIdx.z;
  if (zt >= mt[0]) return;
  int e  = mt[1 + 2 * zt];
  int m0 = mt[2 + 2 * zt];
  int ce = cnt[e];
  int n0 = blockIdx.x * 64;
  __shared__ unsigned short sA[2][128 * 64];    // 32 KB
  __shared__ unsigned short sB1[2][64 * 64];    // 16 KB
  __shared__ unsigned short sB2[2][64 * 64];    // 16 KB
  const float* W1 = w1 + (size_t)e * IFF * DMODEL;
  const float* W3 = w3 + (size_t)e * IFF * DMODEL;
  int tid = threadIdx.x;
  int lane = tid & 63, wave = tid >> 6;
  int wm = (wave >> 1) * 64, wn = (wave & 1) * 32;
  int lrow = lane & 15, lk = (lane >> 4) * 8;
  int ar = tid >> 1, ac = (tid & 1) * 32;       // A: 2 thr/row x 64B
  int br = tid >> 2, bc = (tid & 3) * 16;       // B: 4 thr/row x 64B (256B runs)
  bool av = (m0 + ar) < ce;
  const unsigned short* aptr = hs2b + (size_t)(av ? tok[e * LL + m0 + ar] : 0) * DMODEL + ac;
  const float* w1p = W1 + (size_t)(n0 + br) * DMODEL + bc;
  const float* w3p = W3 + (size_t)(n0 + br) * DMODEL + bc;
  u16x8 ua0[4], ua1[4];
  f32x4 w1r0[4], w1r1[4], w3r0[4], w3r1[4];
#pragma unroll
  for (int q = 0; q < 4; q++) {
    ua0[q] = *(const u16x8*)(aptr + 8 * q);
    ua1[q] = *(const u16x8*)(aptr + 64 + 8 * q);
    w1r0[q] = *(const f32x4*)(w1p + 4 * q);
    w1r1[q] = *(const f32x4*)(w1p + 64 + 4 * q);
    w3r0[q] = *(const f32x4*)(w3p + 4 * q);
    w3r1[q] = *(const f32x4*)(w3p + 64 + 4 * q);
  }
  f32x4 acc1[4][2] = {}, acc2[4][2] = {};
  const int NT = DMODEL / 64;   // 32, even

#define G1_STEP(PB, TT)                                                      \
  {                                                                          \
    *(u16x8*)&sA[PB][swz64(ar, ac)]      = ua##PB[0];                        \
    *(u16x8*)&sA[PB][swz64(ar, ac + 8)]  = ua##PB[1];                        \
    *(u16x8*)&sA[PB][swz64(ar, ac + 16)] = ua##PB[2];                        \
    *(u16x8*)&sA[PB][swz64(ar, ac + 24)] = ua##PB[3];                        \
    u16x8 h;                                                                 \
    cv8(w1r##PB[0], w1r##PB[1], h); *(u16x8*)&sB1[PB][swz64(br, bc)]     = h;\
    cv8(w1r##PB[2], w1r##PB[3], h); *(u16x8*)&sB1[PB][swz64(br, bc + 8)] = h;\
    cv8(w3r##PB[0], w3r##PB[1], h); *(u16x8*)&sB2[PB][swz64(br, bc)]     = h;\
    cv8(w3r##PB[2], w3r##PB[3], h); *(u16x8*)&sB2[PB][swz64(br, bc + 8)] = h;\
    if ((TT) + 2 < NT) {                                                     \
      int kk = ((TT) + 2) * 64;                                              \
      _Pragma("unroll")                                                      \
      for (int q = 0; q < 4; q++) {                                          \
        ua##PB[q]  = *(const u16x8*)(aptr + kk + 8 * q);                     \
        w1r##PB[q] = *(const f32x4*)(w1p + kk + 4 * q);                      \
        w3r##PB[q] = *(const f32x4*)(w3p + kk + 4 * q);                      \
      }                                                                      \
    }                                                                        \
    pipe_sync();                                                             \
    _Pragma("unroll")                                                        \
    for (int ks = 0; ks < 2; ks++) {                                         \
      int ko = lk + ks * 32;                                                 \
      s16x8 af[4];                                                           \
      _Pragma("unroll")                                                      \
      for (int i = 0; i < 4; i++)                                            \
        af[i] = *(const s16x8*)&sA[PB][swz64(wm + i * 16 + lrow, ko)];       \
      _Pragma("unroll")                                                      \
      for (int ni = 0; ni < 2; ni++) {                                       \
        int r = wn + ni * 16 + lrow;                                         \
        s16x8 b1 = *(const s16x8*)&sB1[PB][swz64(r, ko)];                    \
        s16x8 b2 = *(const s16x8*)&sB2[PB][swz64(r, ko)];                    \
        _Pragma("unroll")                                                    \
        for (int mi = 0; mi < 4; mi++) acc1[mi][ni] = mfma16(af[mi], b1, acc1[mi][ni]); \
        _Pragma("unroll")                                                    \
        for (int mi = 0; mi < 4; mi++) acc2[mi][ni] = mfma16(af[mi], b2, acc2[mi][ni]); \
      }                                                                      \
    }                                                                        \
  }

  for (int t = 0; t < NT; t += 2) { G1_STEP(0, t) G1_STEP(1, t + 1) }
#undef G1_STEP

  int rb = wm + (lane >> 4) * 4, cb = wn + (lane & 15);
  int obase = offs[e];
#pragma unroll
  for (int mi = 0; mi < 4; mi++)
#pragma unroll
    for (int j = 0; j < 4; j++) {
      int row = m0 + rb + mi * 16 + j;
      if (row >= ce) continue;
#pragma unroll
      for (int ni = 0; ni < 2; ni++) {
        int col = n0 + cb + ni * 16;
        float g = acc1[mi][ni][j], u = acc2[mi][ni][j];
        float aval = (g / (1.f + __expf(-g))) * u;
        act[(size_t)(obase + row) * IFF + col] = f2bf(aval);
      }
    }
}

// ---------------- MoE phase 2 (BK=64, compact grid, K-split, depth-2) ----------------
__global__ __launch_bounds__(256, 3) void moe_gemm2_k(
    const unsigned short* __restrict__ act, const float* __restrict__ w2,
    float* __restrict__ g2p,
    const int* __restrict__ tok, const float* __restrict__ gate,
    const int* __restrict__ slot, const int* __restrict__ cnt,
    const int* __restrict__ offs, const int* __restrict__ mt)
{
  int zt = blockIdx.z;
  if (zt >= mt[0]) return;
  int e  = mt[1 + 2 * zt];
  int m0 = mt[2 + 2 * zt];
  int ce = cnt[e];
  int part = blockIdx.y;
  int n0 = blockIdx.x * 64;
  int kbase = part * G2CHUNK;
  const int NT = G2CHUNK / 64;   // 44, even
  __shared__ unsigned short sA[2][128 * 64];    // 32 KB
  __shared__ unsigned short sB[2][64 * 64];     // 16 KB
  const float* W = w2 + (size_t)e * DMODEL * IFF;
  int obase = offs[e];
  int tid = threadIdx.x;
  int lane = tid & 63, wave = tid >> 6;
  int wm = (wave >> 1) * 64, wn = (wave & 1) * 32;
  int lrow = lane & 15, lk = (lane >> 4) * 8;
  int ar = tid >> 1, ac = (tid & 1) * 32;
  int br = tid >> 2, bc = (tid & 3) * 16;
  bool av = (m0 + ar) < ce;
  const unsigned short* aptr = act + (size_t)(obase + (av ? (m0 + ar) : 0)) * IFF + kbase + ac;
  const float* wp = W + (size_t)(n0 + br) * IFF + kbase + bc;
  u16x8 ua0[4], ua1[4];
  f32x4 rw0[4], rw1[4];
#pragma unroll
  for (int q = 0; q < 4; q++) {
    ua0[q] = *(const u16x8*)(aptr + 8 * q);
    ua1[q] = *(const u16x8*)(aptr + 64 + 8 * q);
    rw0[q] = *(const f32x4*)(wp + 4 * q);
    rw1[q] = *(const f32x4*)(wp + 64 + 4 * q);
  }
  f32x4 acc[4][2] = {};

#define G2_STEP(PB, TT)                                                      \
  {                                                                          \
    *(u16x8*)&sA[PB][swz64(ar, ac)]      = ua##PB[0];                        \
    *(u16x8*)&sA[PB][swz64(ar, ac + 8)]  = ua##PB[1];                        \
    *(u16x8*)&sA[PB][swz64(ar, ac + 16)] = ua##PB[2];                        \
    *(u16x8*)&sA[PB][swz64(ar, ac + 24)] = ua##PB[3];                        \
    u16x8 h;                                                                 \
    cv8(rw##PB[0], rw##PB[1], h); *(u16x8*)&sB[PB][swz64(br, bc)]     = h;   \
    cv8(rw##PB[2], rw##PB[3], h); *(u16x8*)&sB[PB][swz64(br, bc + 8)] = h;   \
    if ((TT) + 2 < NT) {                                                     \
      int kk = ((TT) + 2) * 64;                                              \
      _Pragma("unroll")                                                      \
      for (int q = 0; q < 4; q++) {                                          \
        ua##PB[q] = *(const u16x8*)(aptr + kk + 8 * q);                      \
        rw##PB[q] = *(const f32x4*)(wp + kk + 4 * q);                        \
      }                                                                      \
    }                                                                        \
    pipe_sync();                                                             \
    _Pragma("unroll")                                                        \
    for (int ks = 0; ks < 2; ks++) {                                         \
      int ko = lk + ks * 32;                                                 \
      s16x8 af[4];                                                           \
      _Pragma("unroll")                                                      \
      for (int i = 0; i < 4; i++)                                            \
        af[i] = *(const s16x8*)&sA[PB][swz64(wm + i * 16 + lrow, ko)];       \
      _Pragma("unroll")                                                      \
      for (int ni = 0; ni < 2; ni++) {                                       \
        s16x8 b = *(const s16x8*)&sB[PB][swz64(wn + ni * 16 + lrow, ko)];    \
        _Pragma("unroll")                                                    \
        for (int mi = 0; mi < 4; mi++) acc[mi][ni] = mfma16(af[mi], b, acc[mi][ni]); \
      }                                                                      \
    }                                                                        \
  }

  for (int t = 0; t < NT; t += 2) { G2_STEP(0, t) G2_STEP(1, t + 1) }
#undef G2_STEP

  int rb = wm + (lane >> 4) * 4, cb = wn + (lane & 15);
#pragma unroll
  for (int mi = 0; mi < 4; mi++)
#pragma unroll
    for (int j = 0; j < 4; j++) {
      int row = m0 + rb + mi * 16 + j;
      if (row >= ce) continue;
      int t = tok[e * LL + row];
      float g = gate[e * LL + row];
      int s = slot[e * LL + row];
      float* dst = g2p + ((size_t)(part * 2 + s) * LL + t) * DMODEL + n0 + cb;
#pragma unroll
      for (int ni = 0; ni < 2; ni++) dst[ni * 16] = acc[mi][ni][j] * g;
    }
}

// ---------------- combine the (part,slot) planes ----------------
__global__ void moe_combine_k(const float* __restrict__ ys, float* __restrict__ out) {
  size_t i = ((size_t)blockIdx.x * 256 + threadIdx.x) * 4;
  f32x4 s = *(const f32x4*)(ys + i);
#pragma unroll
  for (int p = 1; p < 2 * G2PARTS; p++)
    s += *(const f32x4*)(ys + (size_t)p * LL * DMODEL + i);
  *(f32x4*)(out + i) = s;
}

// ---------------- launch ----------------
extern "C" void kernel_launch(void* const* d_in, const int* in_sizes, int n_in,
                              void* d_out, int out_size, void* d_ws, size_t ws_size,
                              hipStream_t stream)
{
  (void)in_sizes; (void)n_in; (void)out_size; (void)ws_size;
  const float* hidden     = (const float*)d_in[0];
  const float* ln_in_w    = (const float*)d_in[1];
  const float* in_proj_w  = (const float*)d_in[2];
  const float* conv_w     = (const float*)d_in[3];
  const float* conv_b     = (const float*)d_in[4];
  const float* x_proj_w   = (const float*)d_in[5];
  const float* dt_ln_w    = (const float*)d_in[6];
  const float* b_ln_w     = (const float*)d_in[7];
  const float* c_ln_w     = (const float*)d_in[8];
  const float* dt_proj_w  = (const float*)d_in[9];
  const float* dt_proj_b  = (const float*)d_in[10];
  const float* A_log      = (const float*)d_in[11];
  const float* D_param    = (const float*)d_in[12];
  const float* out_proj_w = (const float*)d_in[13];
  const float* ln_ff_w    = (const float*)d_in[14];
  const float* router_w   = (const float*)d_in[15];
  const float* w1         = (const float*)d_in[16];
  const float* w3         = (const float*)d_in[17];
  const float* w2         = (const float*)d_in[18];
  float* moe_out  = (float*)d_out;
  float* residual = (float*)d_out + (size_t)LL * DMODEL;

  char* p = (char*)d_ws;
  auto alloc = [&](size_t bytes) { char* r = p; p += (bytes + 255) & ~(size_t)255; return r; };
  unsigned short* hs_hi  = (unsigned short*)alloc((size_t)LL * DMODEL * 2);
  unsigned short* hs_lo  = (unsigned short*)alloc((size_t)LL * DMODEL * 2);
  float* xz              = (float*)alloc((size_t)LL * 2 * DI * 4);   // aliased: out_parts, act_buf
  float* xc              = (float*)alloc((size_t)LL * DI * 4);       // conv out; scan writes y in place
  float* xdb             = (float*)alloc((size_t)LL * 160 * 4);
  float* dtr             = (float*)alloc((size_t)LL * 128 * 4);
  float* Bm              = (float*)alloc((size_t)LL * 16 * 4);
  float* Cm              = (float*)alloc((size_t)LL * 16 * 4);
  float* dt_full         = (float*)alloc((size_t)LL * DI * 4);       // aliased: xdb_parts
  float* mamba_out       = (float*)alloc((size_t)LL * DMODEL * 4);
  float* hs2_f           = (float*)alloc((size_t)LL * DMODEL * 4);
  unsigned short* hs2_bf = (unsigned short*)alloc((size_t)LL * DMODEL * 2);
  int* topi              = (int*)alloc(LL * 2 * 4);
  float* topv            = (float*)alloc(LL * 2 * 4);
  int* tok               = (int*)alloc(NEXP * LL * 4);
  float* gate            = (float*)alloc(NEXP * LL * 4);
  int* slot              = (int*)alloc(NEXP * LL * 4);
  int* cnt               = (int*)alloc(256);
  int* offs              = (int*)alloc(256);
  int* mt                = (int*)alloc((1 + 2 * 64) * 4);   // tile list: count + (e,m0) pairs
  // aliases (lifetimes strictly ordered by stream order):
  float* xdb_parts        = dt_full;               // 16 x 0.655 MB = 10.5 <= 16.78
  float* out_parts        = xz;                    // 4 x 8.39 MB = 33.55 (xz dead after scan)
  unsigned short* act_buf = (unsigned short*)xz;   // 23.07 MB (after out-reduce)
  float* g2parts          = (float*)((char*)act_buf + (size_t)2 * LL * IFF * 2); // 33.55 MB
  //   g2parts spans [23.1, 56.6) MB rel xz: overlaps xz-tail/xc/xdb/dtr — all dead
  //   by moe_gemm2 time; hs2_bf / tok / gate / slot / cnt / offs / mt live beyond it.

  rmsnorm_k<<<LL, 256, 0, stream>>>(hidden, ln_in_w, nullptr, nullptr, nullptr, hs_hi, hs_lo, nullptr);
  gemm_split_k<0, 1><<<dim3(64, 8, 1), 256, 0, stream>>>(nullptr, hs_hi, hs_lo, in_proj_w, xz, LL, 2 * DI, DMODEL, DMODEL, nullptr);
  conv_silu_k<<<(LL * DI) / 256, 256, 0, stream>>>(xz, conv_w, conv_b, xc);
  gemm_split_k<0, 0><<<dim3(2, 8, 16), 256, 0, stream>>>(xc, nullptr, nullptr, x_proj_w, xdb_parts, LL, 160, DI, DI / 16, nullptr);
  reduce_parts_k<<<(LL * 160) / 1024, 256, 0, stream>>>(xdb_parts, xdb, LL * 160, 16);
  dtbc_norm_k<<<LL, 64, 0, stream>>>(xdb, dt_ln_w, b_ln_w, c_ln_w, dtr, Bm, Cm);
  gemm_split_k<1, 0><<<dim3(32, 8, 1), 256, 0, stream>>>(dtr, nullptr, nullptr, dt_proj_w, dt_full, LL, DI, RDT, RDT, dt_proj_b);
  scan_k<<<DI / 16, 256, 0, stream>>>(dt_full, xc, xz, Bm, Cm, A_log, D_param);
  gemm_split_k<0, 0><<<dim3(16, 8, 4), 256, 0, stream>>>(xc, nullptr, nullptr, out_proj_w, out_parts, LL, DMODEL, DI, DI / 4, nullptr);
  reduce_parts_k<<<(LL * DMODEL) / 1024, 256, 0, stream>>>(out_parts, mamba_out, LL * DMODEL, 4);
  rmsnorm_k<<<LL, 256, 0, stream>>>(mamba_out, ln_ff_w, hidden, residual, hs2_f, nullptr, nullptr, hs2_bf);
  router_topk_k<<<LL, 64, 0, stream>>>(hs2_f, router_w, topi, topv);
  build_lists_k<<<1, 64, 0, stream>>>(topi, topv, tok, gate, slot, cnt, offs, mt);
  moe_gemm1_k<<<dim3(88, 1, MAXTILES), 256, 0, stream>>>(hs2_bf, w1, w3, act_buf, tok, cnt, offs, mt);
  moe_gemm2_k<<<dim3(32, G2PARTS, MAXTILES), 256, 0, stream>>>(act_buf, w2, g2parts, tok, gate, slot, cnt, offs, mt);
  moe_combine_k<<<(LL * DMODEL) / (256 * 4), 256, 0, stream>>>(g2parts, moe_out);
}

// Round 11
// 905.600 us; speedup vs baseline: 1.1926x; 1.0000x over previous
//
#include <hip/hip_runtime.h>
#include <hip/hip_bf16.h>
#include <stdint.h>

// ---------------- types / helpers ----------------
typedef __attribute__((ext_vector_type(4))) float f32x4;
typedef __attribute__((ext_vector_type(8))) short s16x8;          // MFMA bf16 frag
typedef __attribute__((ext_vector_type(8))) unsigned short u16x8;

#define LL 1024
#define DMODEL 2048
#define DI 4096
#define NSTATE 16
#define RDT 128
#define NEXP 8
#define IFF 5632

#define BM 128
#define BN 128
#define BK 32
#define G2CHUNK 2816   // moe_gemm2 K-split chunk (2 parts; BK=64 -> NT=44 even)
#define G2PARTS 2
#define MAXTILES 23    // worst-case sum over experts of ceil(ce/128), sum ce = 2048

__device__ inline unsigned short f2bf(float f) {            // fp32 -> bf16 RNE (bit ops)
  unsigned int u = __builtin_bit_cast(unsigned int, f);
  u += 0x7fffu + ((u >> 16) & 1u);
  return (unsigned short)(u >> 16);
}
__device__ inline unsigned short cvbf(float f) {            // compiler path (v_cvt capable)
  return __builtin_bit_cast(unsigned short, __float2bfloat16(f));
}
__device__ inline float upbf(unsigned short h) {
  return __builtin_bit_cast(float, (unsigned int)h << 16);
}
__device__ inline float wred64(float v) {
#pragma unroll
  for (int m = 32; m; m >>= 1) v += __shfl_xor(v, m, 64);
  return v;
}
__device__ inline f32x4 mfma16(s16x8 a, s16x8 b, f32x4 c) {
  return __builtin_amdgcn_mfma_f32_16x16x32_bf16(a, b, c, 0, 0, 0);
}
// LDS tile index, 32-elem rows (mamba GEMMs): XOR-swizzle 8-elem granules
__device__ inline int swz(int row, int chunk) {
  return row * 32 + (chunk ^ ((row & 3) << 3));
}
// LDS tile index, 64-elem rows (MoE GEMMs, BK=64)
__device__ inline int swz64(int row, int chunk) {
  return row * 64 + (chunk ^ ((row & 7) << 3));
}
__device__ inline void cv8(f32x4 a, f32x4 b, u16x8& h) {
#pragma unroll
  for (int j = 0; j < 4; j++) { h[j] = cvbf(a[j]); h[4 + j] = cvbf(b[j]); }
}
__device__ inline void cv_split8(f32x4 a, f32x4 b, u16x8& h, u16x8& l) {
#pragma unroll
  for (int j = 0; j < 4; j++) {
    unsigned short hh = cvbf(a[j]); h[j] = hh; l[j] = cvbf(a[j] - upbf(hh));
    unsigned short hb = cvbf(b[j]); h[4 + j] = hb; l[4 + j] = cvbf(b[j] - upbf(hb));
  }
}
// Barrier WITHOUT the compiler's vmcnt(0) drain (T4-minimum).
__device__ inline void pipe_sync() {
  __builtin_amdgcn_sched_barrier(0);
  asm volatile("s_waitcnt lgkmcnt(0)" ::: "memory");
  __builtin_amdgcn_sched_barrier(0);
  __builtin_amdgcn_s_barrier();
  __builtin_amdgcn_sched_barrier(0);
}

// ---------------- RMSNorm (optionally fused residual-add) ----------------
__global__ __launch_bounds__(256) void rmsnorm_k(
    const float* __restrict__ x, const float* __restrict__ w,
    const float* __restrict__ addin, float* __restrict__ resout,
    float* __restrict__ f32out, unsigned short* __restrict__ hiout,
    unsigned short* __restrict__ loout, unsigned short* __restrict__ bfout)
{
  int t = blockIdx.x, tid = threadIdx.x;
  size_t base = (size_t)t * DMODEL + tid * 8;
  f32x4 v0 = *(const f32x4*)(x + base);
  f32x4 v1 = *(const f32x4*)(x + base + 4);
  if (addin) {
    v0 += *(const f32x4*)(addin + base);
    v1 += *(const f32x4*)(addin + base + 4);
  }
  float ss = 0.f;
#pragma unroll
  for (int j = 0; j < 4; j++) ss += v0[j]*v0[j] + v1[j]*v1[j];
  ss = wred64(ss);
  __shared__ float sred[4];
  if ((tid & 63) == 0) sred[tid >> 6] = ss;
  __syncthreads();
  ss = sred[0] + sred[1] + sred[2] + sred[3];
  float sc = rsqrtf(ss * (1.f / DMODEL) + 1e-6f);
  if (resout) {
    *(f32x4*)(resout + base) = v0;
    *(f32x4*)(resout + base + 4) = v1;
  }
  f32x4 w0 = *(const f32x4*)(w + tid * 8);
  f32x4 w1 = *(const f32x4*)(w + tid * 8 + 4);
  f32x4 o0 = v0 * sc * w0, o1 = v1 * sc * w1;
  if (f32out) {
    *(f32x4*)(f32out + base) = o0;
    *(f32x4*)(f32out + base + 4) = o1;
  }
  if (hiout) {
    u16x8 h, l;
    cv_split8(o0, o1, h, l);
    *(u16x8*)(hiout + base) = h;
    *(u16x8*)(loout + base) = l;
  }
  if (bfout) {
    u16x8 ob;
#pragma unroll
    for (int j = 0; j < 4; j++) { ob[j] = f2bf(o0[j]); ob[4 + j] = f2bf(o1[j]); }
    *(u16x8*)(bfout + base) = ob;
  }
}

// ---------------- split-bf16 GEMM (depth-2 prefetch, dbuf LDS, 1 raw barrier/tile) ----
template<int EPI, int PS>
__global__ __launch_bounds__(256) void gemm_split_k(
    const float* __restrict__ A, const unsigned short* __restrict__ Ah,
    const unsigned short* __restrict__ Al, const float* __restrict__ W,
    float* __restrict__ C, int M, int N, int K, int kchunk,
    const float* __restrict__ bias)
{
  __shared__ unsigned short sA[2][2][128 * 32];   // [dbuf][hi/lo]
  __shared__ unsigned short sB[2][2][128 * 32];
  int tid = threadIdx.x;
  int n0 = blockIdx.x * BN, m0 = blockIdx.y * BM;
  int kbase = blockIdx.z * kchunk;
  C += (size_t)blockIdx.z * M * N;
  int lane = tid & 63, wave = tid >> 6;
  int wm = (wave >> 1) * 64, wn = (wave & 1) * 64;
  int lrow = lane & 15, lk = (lane >> 4) * 8;
  int ar = tid >> 1, ac = (tid & 1) * 16;
  int arow = m0 + ar; if (arow >= M) arow = M - 1;
  int wrow = n0 + ar; if (wrow >= N) wrow = N - 1;
  const float* aptr = A + (size_t)arow * K + kbase + ac;            // unused if PS
  const unsigned short* ahp = Ah + (PS ? ((size_t)arow * K + kbase + ac) : 0);
  const unsigned short* alp = Al + (PS ? ((size_t)arow * K + kbase + ac) : 0);
  const float* wptr = W + (size_t)wrow * K + kbase + ac;
  const int NT = kchunk / BK;          // all callers: NT even, >= 4
  f32x4 ra0[4], ra1[4], rw0[4], rw1[4];
  u16x8 rah0[2], ral0[2], rah1[2], ral1[2];
  if constexpr (PS) {
    rah0[0] = *(const u16x8*)(ahp);      rah0[1] = *(const u16x8*)(ahp + 8);
    ral0[0] = *(const u16x8*)(alp);      ral0[1] = *(const u16x8*)(alp + 8);
    rah1[0] = *(const u16x8*)(ahp + BK); rah1[1] = *(const u16x8*)(ahp + BK + 8);
    ral1[0] = *(const u16x8*)(alp + BK); ral1[1] = *(const u16x8*)(alp + BK + 8);
  } else {
#pragma unroll
    for (int q = 0; q < 4; q++) {
      ra0[q] = *(const f32x4*)(aptr + 4 * q);
      ra1[q] = *(const f32x4*)(aptr + BK + 4 * q);
    }
  }
#pragma unroll
  for (int q = 0; q < 4; q++) {
    rw0[q] = *(const f32x4*)(wptr + 4 * q);
    rw1[q] = *(const f32x4*)(wptr + BK + 4 * q);
  }
  f32x4 acc[4][4] = {};
  int c0 = ac, c1 = ac + 8;

#define GS_STEP(PB, TT)                                                      \
  {                                                                          \
    if constexpr (PS) {                                                      \
      *(u16x8*)&sA[PB][0][swz(ar, c0)] = rah##PB[0];                         \
      *(u16x8*)&sA[PB][0][swz(ar, c1)] = rah##PB[1];                         \
      *(u16x8*)&sA[PB][1][swz(ar, c0)] = ral##PB[0];                         \
      *(u16x8*)&sA[PB][1][swz(ar, c1)] = ral##PB[1];                         \
    } else {                                                                 \
      u16x8 h0, l0, h1, l1;                                                  \
      cv_split8(ra##PB[0], ra##PB[1], h0, l0);                               \
      cv_split8(ra##PB[2], ra##PB[3], h1, l1);                               \
      *(u16x8*)&sA[PB][0][swz(ar, c0)] = h0;                                 \
      *(u16x8*)&sA[PB][1][swz(ar, c0)] = l0;                                 \
      *(u16x8*)&sA[PB][0][swz(ar, c1)] = h1;                                 \
      *(u16x8*)&sA[PB][1][swz(ar, c1)] = l1;                                 \
    }                                                                        \
    {                                                                        \
      u16x8 h0, l0, h1, l1;                                                  \
      cv_split8(rw##PB[0], rw##PB[1], h0, l0);                               \
      cv_split8(rw##PB[2], rw##PB[3], h1, l1);                               \
      *(u16x8*)&sB[PB][0][swz(ar, c0)] = h0;                                 \
      *(u16x8*)&sB[PB][1][swz(ar, c0)] = l0;                                 \
      *(u16x8*)&sB[PB][0][swz(ar, c1)] = h1;                                 \
      *(u16x8*)&sB[PB][1][swz(ar, c1)] = l1;                                 \
    }                                                                        \
    if ((TT) + 2 < NT) {                                                     \
      int kk = ((TT) + 2) * BK;                                              \
      if constexpr (PS) {                                                    \
        rah##PB[0] = *(const u16x8*)(ahp + kk);                              \
        rah##PB[1] = *(const u16x8*)(ahp + kk + 8);                          \
        ral##PB[0] = *(const u16x8*)(alp + kk);                              \
        ral##PB[1] = *(const u16x8*)(alp + kk + 8);                          \
      } else {                                                               \
        _Pragma("unroll")                                                    \
        for (int q = 0; q < 4; q++) ra##PB[q] = *(const f32x4*)(aptr + kk + 4 * q); \
      }                                                                      \
      _Pragma("unroll")                                                      \
      for (int q = 0; q < 4; q++) rw##PB[q] = *(const f32x4*)(wptr + kk + 4 * q); \
    }                                                                        \
    pipe_sync();                                                             \
    {                                                                        \
      s16x8 ah[4], al[4];                                                    \
      _Pragma("unroll")                                                      \
      for (int i = 0; i < 4; i++) {                                          \
        int r = wm + i * 16 + lrow;                                          \
        ah[i] = *(const s16x8*)&sA[PB][0][swz(r, lk)];                       \
        al[i] = *(const s16x8*)&sA[PB][1][swz(r, lk)];                       \
      }                                                                      \
      _Pragma("unroll")                                                      \
      for (int ni = 0; ni < 4; ni++) {                                       \
        int r = wn + ni * 16 + lrow;                                         \
        s16x8 bh = *(const s16x8*)&sB[PB][0][swz(r, lk)];                    \
        s16x8 bl = *(const s16x8*)&sB[PB][1][swz(r, lk)];                    \
        _Pragma("unroll")                                                    \
        for (int mi = 0; mi < 4; mi++) {                                     \
          f32x4 tc = acc[mi][ni];                                            \
          tc = mfma16(al[mi], bh, tc);                                       \
          tc = mfma16(ah[mi], bl, tc);                                       \
          tc = mfma16(ah[mi], bh, tc);                                       \
          acc[mi][ni] = tc;                                                  \
        }                                                                    \
      }                                                                      \
    }                                                                        \
  }

  for (int t = 0; t < NT; t += 2) { GS_STEP(0, t) GS_STEP(1, t + 1) }
#undef GS_STEP

  int rb = wm + (lane >> 4) * 4, cb = wn + (lane & 15);
#pragma unroll
  for (int mi = 0; mi < 4; mi++)
#pragma unroll
    for (int ni = 0; ni < 4; ni++) {
      int col = n0 + cb + ni * 16;
      if (col >= N) continue;
#pragma unroll
      for (int j = 0; j < 4; j++) {
        int row = m0 + rb + mi * 16 + j;
        if (row >= M) continue;
        float v = acc[mi][ni][j];
        if (EPI == 1) { v += bias[col]; v = (v > 20.f) ? v : log1pf(expf(v)); }
        C[(size_t)row * N + col] = v;
      }
    }
}

// ---------------- split-K partial reduction ----------------
__global__ void reduce_parts_k(const float* __restrict__ src, float* __restrict__ dst,
                               int len, int parts)
{
  int i = (blockIdx.x * 256 + threadIdx.x) * 4;
  if (i >= len) return;
  f32x4 s = *(const f32x4*)(src + i);
  for (int p = 1; p < parts; p++) s += *(const f32x4*)(src + (size_t)p * len + i);
  *(f32x4*)(dst + i) = s;
}

// ---------------- causal depthwise conv (K=4) + SiLU ----------------
__global__ __launch_bounds__(256) void conv_silu_k(
    const float* __restrict__ xz, const float* __restrict__ cw,
    const float* __restrict__ cb, float* __restrict__ xc)
{
  int idx = blockIdx.x * 256 + threadIdx.x;      // t*4096 + d
  int t = idx >> 12, d = idx & (DI - 1);
  f32x4 w = *(const f32x4*)(cw + d * 4);
  float acc = cb[d];
#pragma unroll
  for (int k = 0; k < 4; k++) {
    int ts = t - 3 + k;
    if (ts >= 0) acc = fmaf(xz[(size_t)ts * 8192 + d], w[k], acc);
  }
  float v = acc / (1.f + __expf(-acc));
  xc[idx] = v;
}

// ---------------- dt/B/C rmsnorms (row of 160 = 128+16+16) ----------------
__global__ void dtbc_norm_k(const float* __restrict__ xdb,
    const float* __restrict__ dtw, const float* __restrict__ bw, const float* __restrict__ cw,
    float* __restrict__ dtr, float* __restrict__ Bm, float* __restrict__ Cm)
{
  int t = blockIdx.x, lane = threadIdx.x;   // 64 threads
  const float* row = xdb + (size_t)t * 160;
  float v1 = row[lane], v2 = row[64 + lane];
  float vb = (lane < 32) ? row[128 + lane] : 0.f;
  float sd = wred64(v1 * v1 + v2 * v2);
  float sb = wred64((lane < 16) ? vb * vb : 0.f);
  float sc = wred64((lane >= 16 && lane < 32) ? vb * vb : 0.f);
  float scd = rsqrtf(sd * (1.f / 128) + 1e-6f);
  dtr[(size_t)t * 128 + lane]      = v1 * scd * dtw[lane];
  dtr[(size_t)t * 128 + 64 + lane] = v2 * scd * dtw[64 + lane];
  if (lane < 16)      Bm[t * 16 + lane]      = vb * rsqrtf(sb * (1.f / 16) + 1e-6f) * bw[lane];
  else if (lane < 32) Cm[t * 16 + lane - 16] = vb * rsqrtf(sc * (1.f / 16) + 1e-6f) * cw[lane - 16];
}

// ---------------- selective scan; y written IN PLACE over xc ----------------
// 16-way ILP: amortize the 4-level shfl_xor (LDS-pipe latency) across 16
// independent chains. Reduce order per value unchanged (bit-identical).
__global__ __launch_bounds__(256) void scan_k(
    const float* __restrict__ dt, float* __restrict__ xcy,
    const float* __restrict__ xz, const float* __restrict__ Bm,
    const float* __restrict__ Cm, const float* __restrict__ A_log,
    const float* __restrict__ Dp)
{
  __shared__ float sdt[64][16], sxc[64][16], sz[64][16], sB[64][16], sC[64][16], sy[64][16];
  int tid = threadIdx.x;
  int dl = tid >> 4, n = tid & 15;
  int d0 = blockIdx.x * 16;
  int d = d0 + dl;
  float a = -__expf(A_log[d * 16 + n]);
  float dpar = Dp[d];
  float h = 0.f;
  for (int t0 = 0; t0 < LL; t0 += 64) {
#pragma unroll
    for (int i = 0; i < 4; i++) {
      int idx = i * 256 + tid;
      int tt = idx >> 4, c = idx & 15;
      int gt = t0 + tt;
      sdt[tt][c] = dt[(size_t)gt * DI + d0 + c];
      sxc[tt][c] = xcy[(size_t)gt * DI + d0 + c];
      sz[tt][c]  = xz[(size_t)gt * 8192 + DI + d0 + c];
      sB[tt][c]  = Bm[gt * 16 + c];
      sC[tt][c]  = Cm[gt * 16 + c];
    }
    __syncthreads();
    for (int tg = 0; tg < 64; tg += 16) {
      float yv[16];
#pragma unroll
      for (int u = 0; u < 16; u++) {
        int tt = tg + u;
        float dtv = sdt[tt][dl];
        float dA = __expf(dtv * a);
        h = h * dA + dtv * sxc[tt][dl] * sB[tt][n];
        yv[u] = h * sC[tt][n];
      }
#pragma unroll
      for (int u = 0; u < 16; u++) yv[u] += __shfl_xor(yv[u], 1, 64);
#pragma unroll
      for (int u = 0; u < 16; u++) yv[u] += __shfl_xor(yv[u], 2, 64);
#pragma unroll
      for (int u = 0; u < 16; u++) yv[u] += __shfl_xor(yv[u], 4, 64);
#pragma unroll
      for (int u = 0; u < 16; u++) yv[u] += __shfl_xor(yv[u], 8, 64);
      if (n == 0) {
#pragma unroll
        for (int u = 0; u < 16; u++) {
          int tt = tg + u;
          float xv = sxc[tt][dl], zv = sz[tt][dl];
          sy[tt][dl] = (yv[u] + xv * dpar) * (zv / (1.f + __expf(-zv)));
        }
      }
    }
    __syncthreads();
#pragma unroll
    for (int i = 0; i < 4; i++) {
      int idx = i * 256 + tid;
      int tt = idx >> 4, c = idx & 15;
      xcy[(size_t)(t0 + tt) * DI + d0 + c] = sy[tt][c];
    }
    __syncthreads();
  }
}

// ---------------- router: logits + softmax + top-2 ----------------
__global__ void router_topk_k(const float* __restrict__ hs2,
                              const float* __restrict__ rw,
                              int* __restrict__ topi, float* __restrict__ topv)
{
  int t = blockIdx.x, lane = threadIdx.x;   // 64 threads
  float acc[NEXP] = {};
  const float* xr = hs2 + (size_t)t * DMODEL;
  for (int i = lane; i < DMODEL; i += 64) {
    float x = xr[i];
#pragma unroll
    for (int e = 0; e < NEXP; e++) acc[e] += x * rw[e * DMODEL + i];
  }
#pragma unroll
  for (int e = 0; e < NEXP; e++) acc[e] = wred64(acc[e]);
  if (lane == 0) {
    float mx = acc[0];
#pragma unroll
    for (int e = 1; e < NEXP; e++) mx = fmaxf(mx, acc[e]);
    float p[NEXP], s = 0.f;
#pragma unroll
    for (int e = 0; e < NEXP; e++) { p[e] = expf(acc[e] - mx); s += p[e]; }
    float inv = 1.f / s;
#pragma unroll
    for (int e = 0; e < NEXP; e++) p[e] *= inv;
    int i0 = 0;
#pragma unroll
    for (int e = 1; e < NEXP; e++) if (p[e] > p[i0]) i0 = e;
    int i1 = (i0 == 0) ? 1 : 0;
#pragma unroll
    for (int e = 0; e < NEXP; e++) if (e != i0 && p[e] > p[i1]) i1 = e;
    topi[2 * t] = i0; topi[2 * t + 1] = i1;
    topv[2 * t] = p[i0]; topv[2 * t + 1] = p[i1];
  }
}

// ---------------- deterministic per-expert token lists + compact tile list ----------
__global__ void build_lists_k(const int* __restrict__ topi, const float* __restrict__ topv,
                              int* __restrict__ tok, float* __restrict__ gate,
                              int* __restrict__ slot, int* __restrict__ cnt,
                              int* __restrict__ offs, int* __restrict__ mt)
{
  int lane = threadIdx.x;   // 64
  int base[NEXP] = {};
  for (int t0 = 0; t0 < LL; t0 += 64) {
    int t = t0 + lane;
    int i0 = topi[2 * t], i1 = topi[2 * t + 1];
    float p0 = topv[2 * t], p1 = topv[2 * t + 1];
    unsigned long long below = (1ull << lane) - 1ull;
#pragma unroll
    for (int e = 0; e < NEXP; e++) {
      unsigned long long m0 = __ballot(i0 == e);
      if (i0 == e) {
        int pos = base[e] + __popcll(m0 & below);
        tok[e * LL + pos] = t; gate[e * LL + pos] = p0; slot[e * LL + pos] = 0;
      }
      base[e] += __popcll(m0);
      unsigned long long m1 = __ballot(i1 == e);
      if (i1 == e) {
        int pos = base[e] + __popcll(m1 & below);
        tok[e * LL + pos] = t; gate[e * LL + pos] = p1; slot[e * LL + pos] = 1;
      }
      base[e] += __popcll(m1);
    }
  }
  if (lane < NEXP) cnt[lane] = base[lane];
  if (lane == 0) {
    int o = 0;
#pragma unroll
    for (int e = 0; e < NEXP; e++) { offs[e] = o; o += base[e]; }
    int f = 0;
#pragma unroll
    for (int e = 0; e < NEXP; e++)
      for (int m0 = 0; m0 < base[e]; m0 += BM) {
        mt[1 + 2 * f] = e; mt[2 + 2 * f] = m0; f++;
      }
    mt[0] = f;
  }
}

// ---------------- MoE phase 1 (BK=64, 2-phase interleave: loads issued mid-MFMA) ----
__global__ __launch_bounds__(256, 2) void moe_gemm1_k(
    const unsigned short* __restrict__ hs2b,
    const float* __restrict__ w1, const float* __restrict__ w3,
    unsigned short* __restrict__ act,
    const int* __restrict__ tok, const int* __restrict__ cnt,
    const int* __restrict__ offs, const int* __restrict__ mt)
{
  int zt = blockIdx.z;
  if (zt >= mt[0]) return;
  int e  = mt[1 + 2 * zt];
  int m0 = mt[2 + 2 * zt];
  int ce = cnt[e];
  int n0 = blockIdx.x * 64;
  __shared__ unsigned short sA[2][128 * 64];    // 32 KB
  __shared__ unsigned short sB1[2][64 * 64];    // 16 KB
  __shared__ unsigned short sB2[2][64 * 64];    // 16 KB
  const float* W1 = w1 + (size_t)e * IFF * DMODEL;
  const float* W3 = w3 + (size_t)e * IFF * DMODEL;
  int tid = threadIdx.x;
  int lane = tid & 63, wave = tid >> 6;
  int wm = (wave >> 1) * 64, wn = (wave & 1) * 32;
  int lrow = lane & 15, lk = (lane >> 4) * 8;
  int ar = tid >> 1, ac = (tid & 1) * 32;       // A: 2 thr/row x 64B
  int br = tid >> 2, bc = (tid & 3) * 16;       // B: 4 thr/row x 64B (256B runs)
  bool av = (m0 + ar) < ce;
  const unsigned short* aptr = hs2b + (size_t)(av ? tok[e * LL + m0 + ar] : 0) * DMODEL + ac;
  const float* w1p = W1 + (size_t)(n0 + br) * DMODEL + bc;
  const float* w3p = W3 + (size_t)(n0 + br) * DMODEL + bc;
  u16x8 ua0[4], ua1[4];
  f32x4 w1r0[4], w1r1[4], w3r0[4], w3r1[4];
#pragma unroll
  for (int q = 0; q < 4; q++) {
    ua0[q] = *(const u16x8*)(aptr + 8 * q);
    ua1[q] = *(const u16x8*)(aptr + 64 + 8 * q);
    w1r0[q] = *(const f32x4*)(w1p + 4 * q);
    w1r1[q] = *(const f32x4*)(w1p + 64 + 4 * q);
    w3r0[q] = *(const f32x4*)(w3p + 4 * q);
    w3r1[q] = *(const f32x4*)(w3p + 64 + 4 * q);
  }
  f32x4 acc1[4][2] = {}, acc2[4][2] = {};
  const int NT = DMODEL / 64;   // 32, even

  // Per step: stage -> lgkm barrier -> [MFMA ks=0] -> issue prefetch -> [MFMA ks=1].
  // Load issue is spread through the compute phase (vs. pre-barrier burst) so
  // memory requests enter the pipe continuously; setprio(1) keeps MFMA-phase
  // waves fed (T5 applies once phases differ across waves).
#define G1_MFMA(PB, KS)                                                      \
    {                                                                        \
      int ko = lk + (KS) * 32;                                               \
      s16x8 af[4];                                                           \
      _Pragma("unroll")                                                      \
      for (int i = 0; i < 4; i++)                                            \
        af[i] = *(const s16x8*)&sA[PB][swz64(wm + i * 16 + lrow, ko)];       \
      _Pragma("unroll")                                                      \
      for (int ni = 0; ni < 2; ni++) {                                       \
        int r = wn + ni * 16 + lrow;                                         \
        s16x8 b1 = *(const s16x8*)&sB1[PB][swz64(r, ko)];                    \
        s16x8 b2 = *(const s16x8*)&sB2[PB][swz64(r, ko)];                    \
        _Pragma("unroll")                                                    \
        for (int mi = 0; mi < 4; mi++) acc1[mi][ni] = mfma16(af[mi], b1, acc1[mi][ni]); \
        _Pragma("unroll")                                                    \
        for (int mi = 0; mi < 4; mi++) acc2[mi][ni] = mfma16(af[mi], b2, acc2[mi][ni]); \
      }                                                                      \
    }

#define G1_STEP(PB, TT)                                                      \
  {                                                                          \
    *(u16x8*)&sA[PB][swz64(ar, ac)]      = ua##PB[0];                        \
    *(u16x8*)&sA[PB][swz64(ar, ac + 8)]  = ua##PB[1];                        \
    *(u16x8*)&sA[PB][swz64(ar, ac + 16)] = ua##PB[2];                        \
    *(u16x8*)&sA[PB][swz64(ar, ac + 24)] = ua##PB[3];                        \
    u16x8 h;                                                                 \
    cv8(w1r##PB[0], w1r##PB[1], h); *(u16x8*)&sB1[PB][swz64(br, bc)]     = h;\
    cv8(w1r##PB[2], w1r##PB[3], h); *(u16x8*)&sB1[PB][swz64(br, bc + 8)] = h;\
    cv8(w3r##PB[0], w3r##PB[1], h); *(u16x8*)&sB2[PB][swz64(br, bc)]     = h;\
    cv8(w3r##PB[2], w3r##PB[3], h); *(u16x8*)&sB2[PB][swz64(br, bc + 8)] = h;\
    pipe_sync();                                                             \
    __builtin_amdgcn_s_setprio(1);                                           \
    G1_MFMA(PB, 0)                                                           \
    __builtin_amdgcn_s_setprio(0);                                           \
    if ((TT) + 2 < NT) {                                                     \
      int kk = ((TT) + 2) * 64;                                              \
      _Pragma("unroll")                                                      \
      for (int q = 0; q < 4; q++) {                                          \
        ua##PB[q]  = *(const u16x8*)(aptr + kk + 8 * q);                     \
        w1r##PB[q] = *(const f32x4*)(w1p + kk + 4 * q);                      \
        w3r##PB[q] = *(const f32x4*)(w3p + kk + 4 * q);                      \
      }                                                                      \
    }                                                                        \
    __builtin_amdgcn_s_setprio(1);                                           \
    G1_MFMA(PB, 1)                                                           \
    __builtin_amdgcn_s_setprio(0);                                           \
  }

  for (int t = 0; t < NT; t += 2) { G1_STEP(0, t) G1_STEP(1, t + 1) }
#undef G1_STEP
#undef G1_MFMA

  int rb = wm + (lane >> 4) * 4, cb = wn + (lane & 15);
  int obase = offs[e];
#pragma unroll
  for (int mi = 0; mi < 4; mi++)
#pragma unroll
    for (int j = 0; j < 4; j++) {
      int row = m0 + rb + mi * 16 + j;
      if (row >= ce) continue;
#pragma unroll
      for (int ni = 0; ni < 2; ni++) {
        int col = n0 + cb + ni * 16;
        float g = acc1[mi][ni][j], u = acc2[mi][ni][j];
        float aval = (g / (1.f + __expf(-g))) * u;
        act[(size_t)(obase + row) * IFF + col] = f2bf(aval);
      }
    }
}

// ---------------- MoE phase 2 (BK=64, 2-phase interleave, K-split) ----------------
__global__ __launch_bounds__(256, 3) void moe_gemm2_k(
    const unsigned short* __restrict__ act, const float* __restrict__ w2,
    float* __restrict__ g2p,
    const int* __restrict__ tok, const float* __restrict__ gate,
    const int* __restrict__ slot, const int* __restrict__ cnt,
    const int* __restrict__ offs, const int* __restrict__ mt)
{
  int zt = blockIdx.z;
  if (zt >= mt[0]) return;
  int e  = mt[1 + 2 * zt];
  int m0 = mt[2 + 2 * zt];
  int ce = cnt[e];
  int part = blockIdx.y;
  int n0 = blockIdx.x * 64;
  int kbase = part * G2CHUNK;
  const int NT = G2CHUNK / 64;   // 44, even
  __shared__ unsigned short sA[2][128 * 64];    // 32 KB
  __shared__ unsigned short sB[2][64 * 64];     // 16 KB
  const float* W = w2 + (size_t)e * DMODEL * IFF;
  int obase = offs[e];
  int tid = threadIdx.x;
  int lane = tid & 63, wave = tid >> 6;
  int wm = (wave >> 1) * 64, wn = (wave & 1) * 32;
  int lrow = lane & 15, lk = (lane >> 4) * 8;
  int ar = tid >> 1, ac = (tid & 1) * 32;
  int br = tid >> 2, bc = (tid & 3) * 16;
  bool av = (m0 + ar) < ce;
  const unsigned short* aptr = act + (size_t)(obase + (av ? (m0 + ar) : 0)) * IFF + kbase + ac;
  const float* wp = W + (size_t)(n0 + br) * IFF + kbase + bc;
  u16x8 ua0[4], ua1[4];
  f32x4 rw0[4], rw1[4];
#pragma unroll
  for (int q = 0; q < 4; q++) {
    ua0[q] = *(const u16x8*)(aptr + 8 * q);
    ua1[q] = *(const u16x8*)(aptr + 64 + 8 * q);
    rw0[q] = *(const f32x4*)(wp + 4 * q);
    rw1[q] = *(const f32x4*)(wp + 64 + 4 * q);
  }
  f32x4 acc[4][2] = {};

#define G2_MFMA(PB, KS)                                                      \
    {                                                                        \
      int ko = lk + (KS) * 32;                                               \
      s16x8 af[4];                                                           \
      _Pragma("unroll")                                                      \
      for (int i = 0; i < 4; i++)                                            \
        af[i] = *(const s16x8*)&sA[PB][swz64(wm + i * 16 + lrow, ko)];       \
      _Pragma("unroll")                                                      \
      for (int ni = 0; ni < 2; ni++) {                                       \
        s16x8 b = *(const s16x8*)&sB[PB][swz64(wn + ni * 16 + lrow, ko)];    \
        _Pragma("unroll")                                                    \
        for (int mi = 0; mi < 4; mi++) acc[mi][ni] = mfma16(af[mi], b, acc[mi][ni]); \
      }                                                                      \
    }

#define G2_STEP(PB, TT)                                                      \
  {                                                                          \
    *(u16x8*)&sA[PB][swz64(ar, ac)]      = ua##PB[0];                        \
    *(u16x8*)&sA[PB][swz64(ar, ac + 8)]  = ua##PB[1];                        \
    *(u16x8*)&sA[PB][swz64(ar, ac + 16)] = ua##PB[2];                        \
    *(u16x8*)&sA[PB][swz64(ar, ac + 24)] = ua##PB[3];                        \
    u16x8 h;                                                                 \
    cv8(rw##PB[0], rw##PB[1], h); *(u16x8*)&sB[PB][swz64(br, bc)]     = h;   \
    cv8(rw##PB[2], rw##PB[3], h); *(u16x8*)&sB[PB][swz64(br, bc + 8)] = h;   \
    pipe_sync();                                                             \
    __builtin_amdgcn_s_setprio(1);                                           \
    G2_MFMA(PB, 0)                                                           \
    __builtin_amdgcn_s_setprio(0);                                           \
    if ((TT) + 2 < NT) {                                                     \
      int kk = ((TT) + 2) * 64;                                              \
      _Pragma("unroll")                                                      \
      for (int q = 0; q < 4; q++) {                                          \
        ua##PB[q] = *(const u16x8*)(aptr + kk + 8 * q);                      \
        rw##PB[q] = *(const f32x4*)(wp + kk + 4 * q);                        \
      }                                                                      \
    }                                                                        \
    __builtin_amdgcn_s_setprio(1);                                           \
    G2_MFMA(PB, 1)                                                           \
    __builtin_amdgcn_s_setprio(0);                                           \
  }

  for (int t = 0; t < NT; t += 2) { G2_STEP(0, t) G2_STEP(1, t + 1) }
#undef G2_STEP
#undef G2_MFMA

  int rb = wm + (lane >> 4) * 4, cb = wn + (lane & 15);
#pragma unroll
  for (int mi = 0; mi < 4; mi++)
#pragma unroll
    for (int j = 0; j < 4; j++) {
      int row = m0 + rb + mi * 16 + j;
      if (row >= ce) continue;
      int t = tok[e * LL + row];
      float g = gate[e * LL + row];
      int s = slot[e * LL + row];
      float* dst = g2p + ((size_t)(part * 2 + s) * LL + t) * DMODEL + n0 + cb;
#pragma unroll
      for (int ni = 0; ni < 2; ni++) dst[ni * 16] = acc[mi][ni][j] * g;
    }
}

// ---------------- combine the (part,slot) planes ----------------
__global__ void moe_combine_k(const float* __restrict__ ys, float* __restrict__ out) {
  size_t i = ((size_t)blockIdx.x * 256 + threadIdx.x) * 4;
  f32x4 s = *(const f32x4*)(ys + i);
#pragma unroll
  for (int p = 1; p < 2 * G2PARTS; p++)
    s += *(const f32x4*)(ys + (size_t)p * LL * DMODEL + i);
  *(f32x4*)(out + i) = s;
}

// ---------------- launch ----------------
extern "C" void kernel_launch(void* const* d_in, const int* in_sizes, int n_in,
                              void* d_out, int out_size, void* d_ws, size_t ws_size,
                              hipStream_t stream)
{
  (void)in_sizes; (void)n_in; (void)out_size; (void)ws_size;
  const float* hidden     = (const float*)d_in[0];
  const float* ln_in_w    = (const float*)d_in[1];
  const float* in_proj_w  = (const float*)d_in[2];
  const float* conv_w     = (const float*)d_in[3];
  const float* conv_b     = (const float*)d_in[4];
  const float* x_proj_w   = (const float*)d_in[5];
  const float* dt_ln_w    = (const float*)d_in[6];
  const float* b_ln_w     = (const float*)d_in[7];
  const float* c_ln_w     = (const float*)d_in[8];
  const float* dt_proj_w  = (const float*)d_in[9];
  const float* dt_proj_b  = (const float*)d_in[10];
  const float* A_log      = (const float*)d_in[11];
  const float* D_param    = (const float*)d_in[12];
  const float* out_proj_w = (const float*)d_in[13];
  const float* ln_ff_w    = (const float*)d_in[14];
  const float* router_w   = (const float*)d_in[15];
  const float* w1         = (const float*)d_in[16];
  const float* w3         = (const float*)d_in[17];
  const float* w2         = (const float*)d_in[18];
  float* moe_out  = (float*)d_out;
  float* residual = (float*)d_out + (size_t)LL * DMODEL;

  char* p = (char*)d_ws;
  auto alloc = [&](size_t bytes) { char* r = p; p += (bytes + 255) & ~(size_t)255; return r; };
  unsigned short* hs_hi  = (unsigned short*)alloc((size_t)LL * DMODEL * 2);
  unsigned short* hs_lo  = (unsigned short*)alloc((size_t)LL * DMODEL * 2);
  float* xz              = (float*)alloc((size_t)LL * 2 * DI * 4);   // aliased: out_parts, act_buf
  float* xc              = (float*)alloc((size_t)LL * DI * 4);       // conv out; scan writes y in place
  float* xdb             = (float*)alloc((size_t)LL * 160 * 4);
  float* dtr             = (float*)alloc((size_t)LL * 128 * 4);
  float* Bm              = (float*)alloc((size_t)LL * 16 * 4);
  float* Cm              = (float*)alloc((size_t)LL * 16 * 4);
  float* dt_full         = (float*)alloc((size_t)LL * DI * 4);       // aliased: xdb_parts
  float* mamba_out       = (float*)alloc((size_t)LL * DMODEL * 4);
  float* hs2_f           = (float*)alloc((size_t)LL * DMODEL * 4);
  unsigned short* hs2_bf = (unsigned short*)alloc((size_t)LL * DMODEL * 2);
  int* topi              = (int*)alloc(LL * 2 * 4);
  float* topv            = (float*)alloc(LL * 2 * 4);
  int* tok               = (int*)alloc(NEXP * LL * 4);
  float* gate            = (float*)alloc(NEXP * LL * 4);
  int* slot              = (int*)alloc(NEXP * LL * 4);
  int* cnt               = (int*)alloc(256);
  int* offs              = (int*)alloc(256);
  int* mt                = (int*)alloc((1 + 2 * 64) * 4);   // tile list: count + (e,m0) pairs
  // aliases (lifetimes strictly ordered by stream order):
  float* xdb_parts        = dt_full;               // 16 x 0.655 MB = 10.5 <= 16.78
  float* out_parts        = xz;                    // 4 x 8.39 MB = 33.55 (xz dead after scan)
  unsigned short* act_buf = (unsigned short*)xz;   // 23.07 MB (after out-reduce)
  float* g2parts          = (float*)((char*)act_buf + (size_t)2 * LL * IFF * 2); // 33.55 MB
  //   g2parts spans [23.1, 56.6) MB rel xz: overlaps xz-tail/xc/xdb/dtr — all dead
  //   by moe_gemm2 time; hs2_bf / tok / gate / slot / cnt / offs / mt live beyond it.

  rmsnorm_k<<<LL, 256, 0, stream>>>(hidden, ln_in_w, nullptr, nullptr, nullptr, hs_hi, hs_lo, nullptr);
  gemm_split_k<0, 1><<<dim3(64, 8, 1), 256, 0, stream>>>(nullptr, hs_hi, hs_lo, in_proj_w, xz, LL, 2 * DI, DMODEL, DMODEL, nullptr);
  conv_silu_k<<<(LL * DI) / 256, 256, 0, stream>>>(xz, conv_w, conv_b, xc);
  gemm_split_k<0, 0><<<dim3(2, 8, 16), 256, 0, stream>>>(xc, nullptr, nullptr, x_proj_w, xdb_parts, LL, 160, DI, DI / 16, nullptr);
  reduce_parts_k<<<(LL * 160) / 1024, 256, 0, stream>>>(xdb_parts, xdb, LL * 160, 16);
  dtbc_norm_k<<<LL, 64, 0, stream>>>(xdb, dt_ln_w, b_ln_w, c_ln_w, dtr, Bm, Cm);
  gemm_split_k<1, 0><<<dim3(32, 8, 1), 256, 0, stream>>>(dtr, nullptr, nullptr, dt_proj_w, dt_full, LL, DI, RDT, RDT, dt_proj_b);
  scan_k<<<DI / 16, 256, 0, stream>>>(dt_full, xc, xz, Bm, Cm, A_log, D_param);
  gemm_split_k<0, 0><<<dim3(16, 8, 4), 256, 0, stream>>>(xc, nullptr, nullptr, out_proj_w, out_parts, LL, DMODEL, DI, DI / 4, nullptr);
  reduce_parts_k<<<(LL * DMODEL) / 1024, 256, 0, stream>>>(out_parts, mamba_out, LL * DMODEL, 4);
  rmsnorm_k<<<LL, 256, 0, stream>>>(mamba_out, ln_ff_w, hidden, residual, hs2_f, nullptr, nullptr, hs2_bf);
  router_topk_k<<<LL, 64, 0, stream>>>(hs2_f, router_w, topi, topv);
  build_lists_k<<<1, 64, 0, stream>>>(topi, topv, tok, gate, slot, cnt, offs, mt);
  moe_gemm1_k<<<dim3(88, 1, MAXTILES), 256, 0, stream>>>(hs2_bf, w1, w3, act_buf, tok, cnt, offs, mt);
  moe_gemm2_k<<<dim3(32, G2PARTS, MAXTILES), 256, 0, stream>>>(act_buf, w2, g2parts, tok, gate, slot, cnt, offs, mt);
  moe_combine_k<<<(LL * DMODEL) / (256 * 4), 256, 0, stream>>>(g2parts, moe_out);
}